// Round 3
// baseline (1029.671 us; speedup 1.0000x reference)
//
#include <hip/hip_runtime.h>
#include <hip/hip_bf16.h>
#include <math.h>

// ---------------------------------------------------------------------------
// MLA forward. GEMMs: 256x256 8-phase MFMA schedule (T2 swizzle + counted
// vmcnt + setprio), 32x32x16 MFMA. Attention: wave-per-token.
// ---------------------------------------------------------------------------

typedef __attribute__((ext_vector_type(8))) short short8;
typedef __attribute__((ext_vector_type(4))) short short4x;
typedef __attribute__((ext_vector_type(4))) float floatx4;
typedef __attribute__((ext_vector_type(16))) float floatx16;

__device__ inline float bfbits2f(unsigned short u) {
  union { unsigned int i; float f; } c;
  c.i = ((unsigned int)u) << 16;
  return c.f;
}

#define FENCE() asm volatile("" ::: "memory")
#define BAR()                       \
  do {                              \
    FENCE();                        \
    __builtin_amdgcn_s_barrier();   \
    FENCE();                        \
  } while (0)
#define LGKM0() asm volatile("s_waitcnt lgkmcnt(0)" ::: "memory")
#define VMC(n) asm volatile("s_waitcnt vmcnt(" #n ")" ::: "memory")

// -------------------- 256x256 8-phase bf16 GEMM, B transposed --------------
// C[M][Nreal] (ld ldc) = A[M][K] (bf16, ld lda) x Bt[Npad][K] (bf16, ld K)^T
// Requirements: M % 256 == 0, Npad % 256 == 0, K % 128 == 0.
// 512 threads = 8 waves (2M x 4N); per-wave output 128x64 as 4x2 frags of
// 32x32 (v_mfma_f32_32x32x16_bf16); BK=64 (4 K-slices of 16), 2 K-tiles per
// iteration, 8 phases/iter.
// LDS: 2 bufs x (A 256x64 + B 256x64) bf16 = 128 KB -> 1 block/CU.
// Swizzle: within each 128B row, 16B slot ^= (row&7); applied on the GLOBAL
// source of global_load_lds (linear LDS dest) and on the ds_read side.
// 32x32x16 A/B layout: row(col)=lane&31, k=(lane>>5)*8 + 0..7.
// C/D layout: col=lane&31, row=(reg&3)+8*(reg>>2)+4*(lane>>5).
#define RD_A32(cb, qm)                                                   \
  {                                                                      \
    _Pragma("unroll") for (int f_ = 0; f_ < 2; f_++) {                   \
      _Pragma("unroll") for (int s_ = 0; s_ < 4; s_++) {                 \
        Ar[f_][s_] = *(const short8*)(ldsb + (cb) * 65536 +              \
            (wm * 128 + (qm) * 64 + f_ * 32 + r31) * 128 +               \
            (((s_ * 2 + l5) ^ lx) << 4));                                \
      }                                                                  \
    }                                                                    \
  }

#define RD_B32(cb, qn, Brg)                                              \
  {                                                                      \
    _Pragma("unroll") for (int s_ = 0; s_ < 4; s_++) {                   \
      Brg[s_] = *(const short8*)(ldsb + (cb) * 65536 + 32768 +           \
          (wn * 64 + (qn) * 32 + r31) * 128 +                            \
          (((s_ * 2 + l5) ^ lx) << 4));                                  \
    }                                                                    \
  }

#define MM32(qm, g, B)                                                   \
  {                                                                      \
    _Pragma("unroll") for (int f_ = 0; f_ < 2; f_++) {                   \
      _Pragma("unroll") for (int s_ = 0; s_ < 4; s_++) {                 \
        acc[(qm) * 2 + f_][g] = __builtin_amdgcn_mfma_f32_32x32x16_bf16( \
            Ar[f_][s_], B[s_], acc[(qm) * 2 + f_][g], 0, 0, 0);          \
      }                                                                  \
    }                                                                    \
  }

template <bool OUT_BF16>
__global__ __launch_bounds__(512, 2) void gemm256_8ph(
    const __hip_bfloat16* __restrict__ A, const __hip_bfloat16* __restrict__ Bt,
    void* __restrict__ C, int Nreal, int ldc, int K, int lda, int nbx) {
  __shared__ __hip_bfloat16 lds[2][2][16384];  // [buf][A|B][256*64]
  const int tid = threadIdx.x;
  const int lane = tid & 63;
  const int wave = tid >> 6;
  const int wm = wave >> 2;  // 0..1
  const int wn = wave & 3;   // 0..3
  const int r31 = lane & 31;
  const int l5 = lane >> 5;
  const int lx = lane & 7;

  // XCD-chunked block swizzle (bijective when gridDim %8 == 0).
  const int nwg = gridDim.x;
  int wg = blockIdx.x;
  if ((nwg & 7) == 0) wg = (wg & 7) * (nwg >> 3) + (wg >> 3);
  const int by = wg / nbx;
  const int bx = wg - by * nbx;
  const int m0 = by * 256;
  const int n0 = bx * 256;

  // Staging: thread covers linear units u = i*512+tid of a 128x64 half-tile.
  // LDS dest linear (u*16B); global source pre-swizzled: slot ^= row&7.
  const int lr0 = tid >> 3;                 // local row, i=0 (i=1 adds 64)
  const int sg0 = (tid & 7) ^ (lr0 & 7);    // swizzled source slot
  const __hip_bfloat16* aSrc = A + (size_t)(m0 + lr0) * lda + sg0 * 8;
  const __hip_bfloat16* bSrc = Bt + (size_t)(n0 + lr0) * (size_t)K + sg0 * 8;

  auto stageA = [&](int cb, int h, int kt) {
#pragma unroll
    for (int i = 0; i < 2; i++) {
      const __hip_bfloat16* src = aSrc + (size_t)((h * 128 + i * 64) * lda + kt);
      __builtin_amdgcn_global_load_lds(
          (const __attribute__((address_space(1))) void*)src,
          (__attribute__((address_space(3))) void*)&lds[cb][0]
              [h * 8192 + (i * 512 + tid) * 8],
          16, 0, 0);
    }
  };
  auto stageB = [&](int cb, int h, int kt) {
#pragma unroll
    for (int i = 0; i < 2; i++) {
      const __hip_bfloat16* src = bSrc + (size_t)((h * 128 + i * 64) * K + kt);
      __builtin_amdgcn_global_load_lds(
          (const __attribute__((address_space(1))) void*)src,
          (__attribute__((address_space(3))) void*)&lds[cb][1]
              [h * 8192 + (i * 512 + tid) * 8],
          16, 0, 0);
    }
  };

  floatx16 acc[4][2] = {};      // [qm*2+f][g], 32x32 frags
  short8 Ar[2][4];              // [f][slice]
  short8 Br0[4], Br1[4];        // [slice]
  const char* ldsb = (const char*)&lds[0][0][0];

  // Prologue: buf0 = tile0 (B then A), buf1.B = tile1. 12 loads/thread.
  stageB(0, 0, 0); stageB(0, 1, 0);
  stageA(0, 0, 0); stageA(0, 1, 0);
  stageB(1, 0, 64); stageB(1, 1, 64);
  VMC(4);  // buf0 complete; buf1.B (4 loads) stays in flight
  BAR();

  const int niter = K >> 7;  // 2 K-tiles per iteration
#pragma unroll 1
  for (int it = 0; it < niter; ++it) {
    const int ktc = it * 128;
    const int kt1 = ktc + 64;                          // tile for phases 5-8
    const int t0n = (ktc + 128 < K) ? ktc + 128 : 0;   // buf0 next (clamped)
    const int t1n = (ktc + 192 < K) ? ktc + 192 : 0;   // buf1 next (clamped)

    // p1: compute buf0 Q(qm0,qn0); stage buf1.A h0 (this iter's tile1)
    RD_A32(0, 0); RD_B32(0, 0, Br0);
    stageA(1, 0, kt1);
    BAR(); LGKM0();
    __builtin_amdgcn_s_setprio(1); MM32(0, 0, Br0); __builtin_amdgcn_s_setprio(0);
    BAR();
    // p2: Q(qm0,qn1); stage buf1.A h1
    RD_B32(0, 1, Br1);
    stageA(1, 1, kt1);
    BAR(); LGKM0();
    __builtin_amdgcn_s_setprio(1); MM32(0, 1, Br1); __builtin_amdgcn_s_setprio(0);
    BAR();
    // p3: Q(qm1,qn1); stage buf0.B h0 (next iter) — buf0.B free after p2
    RD_A32(0, 1);
    stageB(0, 0, t0n);
    BAR(); LGKM0();
    __builtin_amdgcn_s_setprio(1); MM32(1, 1, Br1); __builtin_amdgcn_s_setprio(0);
    BAR();
    // p4: Q(qm1,qn0) (regs only); stage buf0.B h1; certify buf1 ready
    stageB(0, 1, t0n);
    BAR();
    __builtin_amdgcn_s_setprio(1); MM32(1, 0, Br0); __builtin_amdgcn_s_setprio(0);
    VMC(4);  // completes prologue-leftover + p1p2 => buf1 fully staged
    BAR();
    // p5: compute buf1 Q(qm0,qn0); stage buf0.A h0 — buf0.A free after p3
    RD_A32(1, 0); RD_B32(1, 0, Br0);
    stageA(0, 0, t0n);
    BAR(); LGKM0();
    __builtin_amdgcn_s_setprio(1); MM32(0, 0, Br0); __builtin_amdgcn_s_setprio(0);
    BAR();
    // p6: Q(qm0,qn1); stage buf0.A h1
    RD_B32(1, 1, Br1);
    stageA(0, 1, t0n);
    BAR(); LGKM0();
    __builtin_amdgcn_s_setprio(1); MM32(0, 1, Br1); __builtin_amdgcn_s_setprio(0);
    BAR();
    // p7: Q(qm1,qn1); stage buf1.B h0 — buf1.B free after p6
    RD_A32(1, 1);
    stageB(1, 0, t1n);
    BAR(); LGKM0();
    __builtin_amdgcn_s_setprio(1); MM32(1, 1, Br1); __builtin_amdgcn_s_setprio(0);
    BAR();
    // p8: Q(qm1,qn0); stage buf1.B h1; certify buf0 ready for next iter
    stageB(1, 1, t1n);
    BAR();
    __builtin_amdgcn_s_setprio(1); MM32(1, 0, Br0); __builtin_amdgcn_s_setprio(0);
    VMC(4);  // completes p3..p6 => buf0 fully staged; p7p8 in flight
    BAR();
  }
  VMC(0);  // drain tail junk stages before LDS teardown

  // Epilogue: 32x32 C/D: col=lane&31, row=(reg&3)+8*(reg>>2)+4*(lane>>5).
#pragma unroll
  for (int fm = 0; fm < 4; fm++) {
#pragma unroll
    for (int g = 0; g < 2; g++) {
      const int col = n0 + wn * 64 + g * 32 + r31;
      if (col < Nreal) {
#pragma unroll
        for (int r = 0; r < 16; r++) {
          const size_t row = (size_t)(m0 + wm * 128 + fm * 32 + (r & 3) +
                                      8 * (r >> 2) + 4 * l5);
          if (OUT_BF16)
            ((__hip_bfloat16*)C)[row * ldc + col] =
                __float2bfloat16(acc[fm][g][r]);
          else
            ((float*)C)[row * ldc + col] = acc[fm][g][r];
        }
      }
    }
  }
}

// -------------------- weight transpose + cast ------------------------------
__global__ __launch_bounds__(256) void transpose_cast(
    const float* __restrict__ in, __hip_bfloat16* __restrict__ out, int K,
    int N) {
  __shared__ float tile[32][33];
  const int n0 = blockIdx.x * 32, k0 = blockIdx.y * 32;
  const int tx = threadIdx.x & 31, ty = threadIdx.x >> 5;
#pragma unroll
  for (int r = 0; r < 32; r += 8) {
    const int k = k0 + ty + r, n = n0 + tx;
    tile[ty + r][tx] = (n < N) ? in[(size_t)k * N + n] : 0.f;
  }
  __syncthreads();
#pragma unroll
  for (int r = 0; r < 32; r += 8) {
    const int n = n0 + ty + r, k = k0 + tx;
    out[(size_t)n * K + k] = __float2bfloat16(tile[tx][ty + r]);
  }
}

// -------------------- x cast ----------------------------------------------
__global__ __launch_bounds__(256) void cast_f32_bf16(
    const float* __restrict__ in, __hip_bfloat16* __restrict__ out) {
  const size_t i = ((size_t)blockIdx.x * 256 + threadIdx.x) * 4;
  const float4 v = *(const float4*)(in + i);
  out[i + 0] = __float2bfloat16(v.x);
  out[i + 1] = __float2bfloat16(v.y);
  out[i + 2] = __float2bfloat16(v.z);
  out[i + 3] = __float2bfloat16(v.w);
}

// -------------------- RMSNorm (bf16 in-place, short8 vectorized) -----------
__global__ __launch_bounds__(256) void rmsnorm_bf16(
    __hip_bfloat16* __restrict__ x, const float* __restrict__ w, int ncols,
    int stride) {
  __hip_bfloat16* xr = x + (size_t)blockIdx.x * stride;
  float ss = 0.f;
  for (int c = threadIdx.x * 8; c < ncols; c += 2048) {
    const short8 v = *(const short8*)(xr + c);
#pragma unroll
    for (int k = 0; k < 8; k++) {
      const float f = bfbits2f((unsigned short)v[k]);
      ss += f * f;
    }
  }
#pragma unroll
  for (int off = 32; off > 0; off >>= 1) ss += __shfl_down(ss, off);
  __shared__ float wsum[4];
  __shared__ float scale_sh;
  const int wv = threadIdx.x >> 6, lane = threadIdx.x & 63;
  if (lane == 0) wsum[wv] = ss;
  __syncthreads();
  if (threadIdx.x == 0) {
    const float tot = wsum[0] + wsum[1] + wsum[2] + wsum[3];
    scale_sh = rsqrtf(tot / (float)ncols + 1e-6f);
  }
  __syncthreads();
  const float scale = scale_sh;
  for (int c = threadIdx.x * 8; c < ncols; c += 2048) {
    const short8 v = *(const short8*)(xr + c);
    short8 o;
#pragma unroll
    for (int k = 0; k < 8; k++) {
      float f = bfbits2f((unsigned short)v[k]) * scale;
      if (w) f *= w[c + k];
      const __hip_bfloat16 b = __float2bfloat16(f);
      o[k] = *(const short*)&b;
    }
    *(short8*)(xr + c) = o;
  }
}

// -------------------- RoPE on q (bug-compatible positions) -----------------
__global__ __launch_bounds__(256) void rope_q_bf16(
    __hip_bfloat16* __restrict__ q, const int* __restrict__ start_pos_p,
    int t0) {
  const int idx = blockIdx.x * 256 + threadIdx.x;  // Tc*16*32
  const int i = idx & 31;
  const int th = idx >> 5;
  const int t = th >> 4;
  const int h = th & 15;
  const int s_idx = (t0 + t) & 4095;
  const int pos = ((s_idx * 16 + h) & 4095) + start_pos_p[0];
  const double theta = pow(10000.0, -(double)i / 32.0);
  const double ang = (double)pos * theta;
  const float c = (float)cos(ang), s = (float)sin(ang);
  __hip_bfloat16* base = q + (size_t)t * 3072 + h * 192 + 128;
  const float x1 = __bfloat162float(base[i]);
  const float x2 = __bfloat162float(base[i + 32]);
  base[i] = __float2bfloat16(x1 * c - x2 * s);
  base[i + 32] = __float2bfloat16(x2 * c + x1 * s);
}

// -------------------- RoPE on k_pe (pos = start_pos) -----------------------
__global__ __launch_bounds__(256) void rope_kpe_bf16(
    __hip_bfloat16* __restrict__ kv, const int* __restrict__ start_pos_p) {
  const int idx = blockIdx.x * 256 + threadIdx.x;  // Tc*32
  const int i = idx & 31;
  const int t = idx >> 5;
  const int pos = start_pos_p[0];
  const double theta = pow(10000.0, -(double)i / 32.0);
  const double ang = (double)pos * theta;
  const float c = (float)cos(ang), s = (float)sin(ang);
  __hip_bfloat16* base = kv + (size_t)t * 576 + 512;
  const float x1 = __bfloat162float(base[i]);
  const float x2 = __bfloat162float(base[i + 32]);
  base[i] = __float2bfloat16(x1 * c - x2 * s);
  base[i + 32] = __float2bfloat16(x2 * c + x1 * s);
}

// -------------------- wave-per-token attention -----------------------------
__global__ __launch_bounds__(256) void attn_wave_token(
    const __hip_bfloat16* __restrict__ q,     // [T][16][192]
    const __hip_bfloat16* __restrict__ kvup,  // [T][16][256] (k_nope|v)
    const __hip_bfloat16* __restrict__ kv,    // [T][576], k_pe at +512
    __hip_bfloat16* __restrict__ ctx) {       // [T][16][128]
  __shared__ __hip_bfloat16 sq[4][16 * 200];
  __shared__ __hip_bfloat16 su[4][16 * 264];
  __shared__ __hip_bfloat16 skpe[4][64];
  __shared__ float sp[4][16][16];
  const int tid = threadIdx.x;
  const int w = tid >> 6;
  const int lane = tid & 63;
  const int t = blockIdx.x * 4 + w;

  const __hip_bfloat16* qb = q + (size_t)t * 3072;
  const __hip_bfloat16* ub = kvup + (size_t)t * 4096;
#pragma unroll
  for (int i = 0; i < 6; i++) {
    const int u = lane + 64 * i;  // u < 384
    const int row = u / 24;
    *(short8*)(&sq[w][u * 8 + row * 8]) = *(const short8*)(qb + u * 8);
  }
#pragma unroll
  for (int i = 0; i < 8; i++) {
    const int u = lane + 64 * i;  // u < 512
    const int row = u >> 5;
    *(short8*)(&su[w][u * 8 + row * 8]) = *(const short8*)(ub + u * 8);
  }
  if (lane < 8)
    *(short8*)(&skpe[w][lane * 8]) =
        *(const short8*)(kv + (size_t)t * 576 + 512 + lane * 8);
  __syncthreads();

  const int qh = lane >> 2;
  const int khb = lane & 3;
  float s[4] = {0.f, 0.f, 0.f, 0.f};
#pragma unroll
  for (int c = 0; c < 128; c += 8) {
    const short8 qv = *(const short8*)(&sq[w][qh * 200 + c]);
    float qf[8];
#pragma unroll
    for (int k = 0; k < 8; k++) qf[k] = bfbits2f((unsigned short)qv[k]);
#pragma unroll
    for (int p = 0; p < 4; p++) {
      const short8 kvv = *(const short8*)(&su[w][(khb + 4 * p) * 264 + c]);
#pragma unroll
      for (int k = 0; k < 8; k++)
        s[p] += qf[k] * bfbits2f((unsigned short)kvv[k]);
    }
  }
#pragma unroll
  for (int c = 0; c < 64; c += 8) {
    const short8 qv = *(const short8*)(&sq[w][qh * 200 + 128 + c]);
    const short8 kvv = *(const short8*)(&skpe[w][c]);
#pragma unroll
    for (int k = 0; k < 8; k++) {
      const float prod =
          bfbits2f((unsigned short)qv[k]) * bfbits2f((unsigned short)kvv[k]);
#pragma unroll
      for (int p = 0; p < 4; p++) s[p] += prod;
    }
  }
  const float scale = 0.07216878364870323f;  // 1/sqrt(192)
#pragma unroll
  for (int p = 0; p < 4; p++) s[p] *= scale;

  float mx = fmaxf(fmaxf(s[0], s[1]), fmaxf(s[2], s[3]));
  mx = fmaxf(mx, __shfl_xor(mx, 1));
  mx = fmaxf(mx, __shfl_xor(mx, 2));
  float e[4], sum = 0.f;
#pragma unroll
  for (int p = 0; p < 4; p++) {
    e[p] = expf(s[p] - mx);
    sum += e[p];
  }
  sum += __shfl_xor(sum, 1);
  sum += __shfl_xor(sum, 2);
  const float inv = 1.0f / sum;
#pragma unroll
  for (int p = 0; p < 4; p++) sp[w][qh][khb + 4 * p] = e[p] * inv;
  __syncthreads();

  const int d0 = (lane & 31) * 4;
  float vreg[16][4];
#pragma unroll
  for (int j = 0; j < 16; j++) {
    const short4x v4 = *(const short4x*)(&su[w][j * 264 + 128 + d0]);
#pragma unroll
    for (int k = 0; k < 4; k++) vreg[j][k] = bfbits2f((unsigned short)v4[k]);
  }
  const int hb = (lane >> 5) * 8;
  __hip_bfloat16* cb = ctx + (size_t)t * 2048;
#pragma unroll
  for (int g = 0; g < 8; g++) {
    const int hh = hb + g;
    float o[4] = {0.f, 0.f, 0.f, 0.f};
#pragma unroll
    for (int j4 = 0; j4 < 4; j4++) {
      const float4 p4 = *(const float4*)(&sp[w][hh][j4 * 4]);
      const float pj[4] = {p4.x, p4.y, p4.z, p4.w};
#pragma unroll
      for (int jj = 0; jj < 4; jj++) {
        const int j = j4 * 4 + jj;
#pragma unroll
        for (int k = 0; k < 4; k++) o[k] += pj[jj] * vreg[j][k];
      }
    }
    short4x st;
#pragma unroll
    for (int k = 0; k < 4; k++) {
      const __hip_bfloat16 b = __float2bfloat16(o[k]);
      st[k] = *(const short*)&b;
    }
    *(short4x*)(cb + hh * 128 + d0) = st;
  }
}

// ---------------------------------------------------------------------------
extern "C" void kernel_launch(void* const* d_in, const int* in_sizes, int n_in,
                              void* d_out, int out_size, void* d_ws,
                              size_t ws_size, hipStream_t stream) {
  const float* x = (const float*)d_in[0];          // 16384 x 2048
  const float* wq_a = (const float*)d_in[1];       // 2048 x 1536
  const float* q_norm_w = (const float*)d_in[2];   // 1536
  const float* wq_b = (const float*)d_in[3];       // 1536 x 3072
  const float* wkv_a = (const float*)d_in[4];      // 2048 x 576
  const float* wkv_b = (const float*)d_in[5];      // 512 x 4096
  const float* wo = (const float*)d_in[6];         // 2048 x 2048
  const int* start_pos = (const int*)d_in[7];
  float* out = (float*)d_out;

  const int T = 16384;
  __hip_bfloat16* w0 = (__hip_bfloat16*)d_ws;
  __hip_bfloat16* wq_aT = w0;                        // 1536 x 2048
  __hip_bfloat16* wq_bT = wq_aT + 1536 * 2048;       // 3072 x 1536
  __hip_bfloat16* wkv_aT = wq_bT + 3072 * 1536;      // 768 x 2048 (zero-pad)
  __hip_bfloat16* wkv_bT = wkv_aT + 768 * 2048;      // 4096 x 512
  __hip_bfloat16* woT = wkv_bT + 4096 * 512;         // 2048 x 2048
  __hip_bfloat16* chunk0 = woT + 2048 * 2048;
  const size_t w_bytes = (size_t)(chunk0 - w0) * sizeof(__hip_bfloat16);

  const size_t per_tok = 11840 * sizeof(__hip_bfloat16);
  int Tc = T;
  while (Tc > 256 && w_bytes + (size_t)Tc * per_tok > ws_size) Tc >>= 1;

  __hip_bfloat16* xb = chunk0;                       // Tc x 2048
  __hip_bfloat16* q_buf = xb + (size_t)Tc * 2048;    // Tc x 3072
  __hip_bfloat16* kvup = q_buf + (size_t)Tc * 3072;  // Tc x 4096
  __hip_bfloat16* cbuf = kvup + (size_t)Tc * 4096;   // Tc x 2048
  __hip_bfloat16* kv = cbuf + (size_t)Tc * 2048;     // Tc x 576

  dim3 blk(256);
  dim3 blk512(512);

  transpose_cast<<<dim3(1536 / 32, 2048 / 32), blk, 0, stream>>>(wq_a, wq_aT,
                                                                 2048, 1536);
  transpose_cast<<<dim3(3072 / 32, 1536 / 32), blk, 0, stream>>>(wq_b, wq_bT,
                                                                 1536, 3072);
  transpose_cast<<<dim3(768 / 32, 2048 / 32), blk, 0, stream>>>(wkv_a, wkv_aT,
                                                                2048, 576);
  transpose_cast<<<dim3(4096 / 32, 512 / 32), blk, 0, stream>>>(wkv_b, wkv_bT,
                                                                512, 4096);
  transpose_cast<<<dim3(2048 / 32, 2048 / 32), blk, 0, stream>>>(wo, woT, 2048,
                                                                 2048);

  const int nby = Tc / 256;
  for (int t0 = 0; t0 < T; t0 += Tc) {
    cast_f32_bf16<<<(Tc * 2048) / 1024, blk, 0, stream>>>(
        x + (size_t)t0 * 2048, xb);
    // G1: q_lora = xb @ wq_a^T -> cbuf
    gemm256_8ph<true><<<dim3(6 * nby), blk512, 0, stream>>>(
        xb, wq_aT, cbuf, 1536, 1536, 2048, 2048, 6);
    rmsnorm_bf16<<<Tc, blk, 0, stream>>>(cbuf, q_norm_w, 1536, 1536);
    // G2: q = q_lora @ wq_b^T
    gemm256_8ph<true><<<dim3(12 * nby), blk512, 0, stream>>>(
        cbuf, wq_bT, q_buf, 3072, 3072, 1536, 1536, 12);
    rope_q_bf16<<<(Tc * 16 * 32) / 256, blk, 0, stream>>>(q_buf, start_pos, t0);
    // G3: kv = xb @ wkv_a^T (Npad=768, store masked to 576)
    gemm256_8ph<true><<<dim3(3 * nby), blk512, 0, stream>>>(
        xb, wkv_aT, kv, 576, 576, 2048, 2048, 3);
    rope_kpe_bf16<<<(Tc * 32) / 256, blk, 0, stream>>>(kv, start_pos);
    rmsnorm_bf16<<<Tc, blk, 0, stream>>>(kv, nullptr, 512, 576);
    // G4: kvup = kvn @ wkv_b^T (A ld 576, K=512)
    gemm256_8ph<true><<<dim3(16 * nby), blk512, 0, stream>>>(
        kv, wkv_bT, kvup, 4096, 4096, 512, 576, 16);
    // attention -> ctx (reuses cbuf)
    attn_wave_token<<<Tc / 4, blk, 0, stream>>>(q_buf, kvup, kv, cbuf);
    // G5: out = ctx @ wo^T (fp32 out)
    gemm256_8ph<false><<<dim3(8 * nby), blk512, 0, stream>>>(
        cbuf, woT, out + (size_t)t0 * 2048, 2048, 2048, 2048, 2048, 8);
  }
}

// Round 4
// 955.128 us; speedup vs baseline: 1.0780x; 1.0780x over previous
//
#include <hip/hip_runtime.h>
#include <hip/hip_bf16.h>
#include <math.h>

// ---------------------------------------------------------------------------
// MLA forward. GEMMs: 256x256 8-phase MFMA schedule (T2 swizzle + counted
// vmcnt + setprio), 16x16x32 MFMA (32x32 variant regressed: bank conflicts).
// RoPE via precomputed cos/sin table (double math done once per (pos,i)).
// G1+G3 fused (shared A, concatenated Bt, split epilogue).
// ---------------------------------------------------------------------------

typedef __attribute__((ext_vector_type(8))) short short8;
typedef __attribute__((ext_vector_type(4))) short short4x;
typedef __attribute__((ext_vector_type(4))) float floatx4;

__device__ inline float bfbits2f(unsigned short u) {
  union { unsigned int i; float f; } c;
  c.i = ((unsigned int)u) << 16;
  return c.f;
}

#define FENCE() asm volatile("" ::: "memory")
#define BAR()                       \
  do {                              \
    FENCE();                        \
    __builtin_amdgcn_s_barrier();   \
    FENCE();                        \
  } while (0)
#define LGKM0()                                       \
  do {                                                \
    asm volatile("s_waitcnt lgkmcnt(0)" ::: "memory");\
    __builtin_amdgcn_sched_barrier(0);                \
  } while (0)
#define VMC(n) asm volatile("s_waitcnt vmcnt(" #n ")" ::: "memory")

// -------------------- 256x256 8-phase bf16 GEMM, B transposed --------------
// C[M][*] = A[M][K] (bf16, ld lda) x Bt[Npad][K] (bf16, ld K)^T
// Columns < Nsplit -> C (ld ldc); columns in [Nsplit, Nsplit+N2) -> C2
// (ld ldc2, col-Nsplit); other columns dropped.
// M % 256 == 0, Npad % 256 == 0, K % 128 == 0.
// 512 threads = 8 waves (2M x 4N); per-wave output 128x64 (8x4 frags of
// 16x16x32); BK=64, 2 K-tiles per iteration, 8 phases/iter.
// LDS: 2 bufs x (A 256x64 + B 256x64) bf16 = 128 KB -> 1 block/CU.
// Swizzle: within each 128B row, 16B slot ^= (row&7); applied on the GLOBAL
// source of global_load_lds (linear LDS dest) and on the ds_read side.
#define RD_A(cb, qm)                                                     \
  {                                                                      \
    _Pragma("unroll") for (int f_ = 0; f_ < 4; f_++) {                   \
      _Pragma("unroll") for (int ks_ = 0; ks_ < 2; ks_++) {              \
        Ar[f_][ks_] = *(const short8*)(ldsb + (cb) * 65536 +             \
            (wm * 128 + (qm) * 64 + f_ * 16 + r15) * 128 +               \
            (((ks_ * 4 + l4) ^ lx) << 4));                               \
      }                                                                  \
    }                                                                    \
  }

#define RD_B(cb, qn, Brg)                                                \
  {                                                                      \
    _Pragma("unroll") for (int g_ = 0; g_ < 2; g_++) {                   \
      _Pragma("unroll") for (int ks_ = 0; ks_ < 2; ks_++) {              \
        Brg[g_][ks_] = *(const short8*)(ldsb + (cb) * 65536 + 32768 +    \
            (wn * 64 + (qn) * 32 + g_ * 16 + r15) * 128 +                \
            (((ks_ * 4 + l4) ^ lx) << 4));                               \
      }                                                                  \
    }                                                                    \
  }

#define MM(qm, qn, B)                                                    \
  {                                                                      \
    _Pragma("unroll") for (int f_ = 0; f_ < 4; f_++) {                   \
      _Pragma("unroll") for (int g_ = 0; g_ < 2; g_++) {                 \
        acc[(qm) * 4 + f_][(qn) * 2 + g_] =                              \
            __builtin_amdgcn_mfma_f32_16x16x32_bf16(                     \
                Ar[f_][0], B[g_][0], acc[(qm) * 4 + f_][(qn) * 2 + g_],  \
                0, 0, 0);                                                \
        acc[(qm) * 4 + f_][(qn) * 2 + g_] =                              \
            __builtin_amdgcn_mfma_f32_16x16x32_bf16(                     \
                Ar[f_][1], B[g_][1], acc[(qm) * 4 + f_][(qn) * 2 + g_],  \
                0, 0, 0);                                                \
      }                                                                  \
    }                                                                    \
  }

template <bool OUT_BF16>
__global__ __launch_bounds__(512, 2) void gemm256_8ph(
    const __hip_bfloat16* __restrict__ A, const __hip_bfloat16* __restrict__ Bt,
    void* __restrict__ C, int Nsplit, int ldc,
    void* __restrict__ C2, int ldc2, int N2,
    int K, int lda, int nbx) {
  __shared__ __hip_bfloat16 lds[2][2][16384];  // [buf][A|B][256*64]
  const int tid = threadIdx.x;
  const int lane = tid & 63;
  const int wave = tid >> 6;
  const int wm = wave >> 2;  // 0..1
  const int wn = wave & 3;   // 0..3
  const int r15 = lane & 15;
  const int l4 = lane >> 4;
  const int lx = lane & 7;

  // XCD-chunked block swizzle (bijective when gridDim %8 == 0).
  const int nwg = gridDim.x;
  int wg = blockIdx.x;
  if ((nwg & 7) == 0) wg = (wg & 7) * (nwg >> 3) + (wg >> 3);
  const int by = wg / nbx;
  const int bx = wg - by * nbx;
  const int m0 = by * 256;
  const int n0 = bx * 256;

  // Staging: thread covers linear units u = i*512+tid of a 128x64 half-tile.
  // LDS dest linear (u*16B); global source pre-swizzled: slot ^= row&7.
  const int lr0 = tid >> 3;                 // local row, i=0 (i=1 adds 64)
  const int sg0 = (tid & 7) ^ (lr0 & 7);    // swizzled source slot
  const __hip_bfloat16* aSrc = A + (size_t)(m0 + lr0) * lda + sg0 * 8;
  const __hip_bfloat16* bSrc = Bt + (size_t)(n0 + lr0) * (size_t)K + sg0 * 8;

  auto stageA = [&](int cb, int h, int kt) {
#pragma unroll
    for (int i = 0; i < 2; i++) {
      const __hip_bfloat16* src = aSrc + (size_t)((h * 128 + i * 64) * lda + kt);
      __builtin_amdgcn_global_load_lds(
          (const __attribute__((address_space(1))) void*)src,
          (__attribute__((address_space(3))) void*)&lds[cb][0]
              [h * 8192 + (i * 512 + tid) * 8],
          16, 0, 0);
    }
  };
  auto stageB = [&](int cb, int h, int kt) {
#pragma unroll
    for (int i = 0; i < 2; i++) {
      const __hip_bfloat16* src = bSrc + (size_t)((h * 128 + i * 64) * K + kt);
      __builtin_amdgcn_global_load_lds(
          (const __attribute__((address_space(1))) void*)src,
          (__attribute__((address_space(3))) void*)&lds[cb][1]
              [h * 8192 + (i * 512 + tid) * 8],
          16, 0, 0);
    }
  };

  floatx4 acc[8][4] = {};
  short8 Ar[4][2], Br0[2][2], Br1[2][2];
  const char* ldsb = (const char*)&lds[0][0][0];

  // Prologue: buf0 = tile0 (B then A), buf1.B = tile1. 12 loads/thread.
  stageB(0, 0, 0); stageB(0, 1, 0);
  stageA(0, 0, 0); stageA(0, 1, 0);
  stageB(1, 0, 64); stageB(1, 1, 64);
  VMC(4);  // buf0 complete; buf1.B (4 loads) stays in flight
  BAR();

  const int niter = K >> 7;  // 2 K-tiles per iteration
#pragma unroll 1
  for (int it = 0; it < niter; ++it) {
    const int ktc = it * 128;
    const int kt1 = ktc + 64;                          // tile for phases 5-8
    const int t0n = (ktc + 128 < K) ? ktc + 128 : 0;   // buf0 next (clamped)
    const int t1n = (ktc + 192 < K) ? ktc + 192 : 0;   // buf1 next (clamped)

    // p1: compute buf0 Q(0,0); stage buf1.A h0 (this iter's tile1)
    RD_A(0, 0); RD_B(0, 0, Br0);
    stageA(1, 0, kt1);
    BAR(); LGKM0();
    __builtin_amdgcn_s_setprio(1); MM(0, 0, Br0); __builtin_amdgcn_s_setprio(0);
    BAR();
    // p2: Q(0,1); stage buf1.A h1
    RD_B(0, 1, Br1);
    stageA(1, 1, kt1);
    BAR(); LGKM0();
    __builtin_amdgcn_s_setprio(1); MM(0, 1, Br1); __builtin_amdgcn_s_setprio(0);
    BAR();
    // p3: Q(1,1); stage buf0.B h0 (next iter) — buf0.B free after p2
    RD_A(0, 1);
    stageB(0, 0, t0n);
    BAR(); LGKM0();
    __builtin_amdgcn_s_setprio(1); MM(1, 1, Br1); __builtin_amdgcn_s_setprio(0);
    BAR();
    // p4: Q(1,0) (regs only); stage buf0.B h1; certify buf1 ready
    stageB(0, 1, t0n);
    BAR();
    __builtin_amdgcn_s_setprio(1); MM(1, 0, Br0); __builtin_amdgcn_s_setprio(0);
    VMC(4);  // completes prologue-leftover + p1p2 => buf1 fully staged
    BAR();
    // p5: compute buf1 Q(0,0); stage buf0.A h0 — buf0.A free after p3
    RD_A(1, 0); RD_B(1, 0, Br0);
    stageA(0, 0, t0n);
    BAR(); LGKM0();
    __builtin_amdgcn_s_setprio(1); MM(0, 0, Br0); __builtin_amdgcn_s_setprio(0);
    BAR();
    // p6: Q(0,1); stage buf0.A h1
    RD_B(1, 1, Br1);
    stageA(0, 1, t0n);
    BAR(); LGKM0();
    __builtin_amdgcn_s_setprio(1); MM(0, 1, Br1); __builtin_amdgcn_s_setprio(0);
    BAR();
    // p7: Q(1,1); stage buf1.B h0 — buf1.B free after p6
    RD_A(1, 1);
    stageB(1, 0, t1n);
    BAR(); LGKM0();
    __builtin_amdgcn_s_setprio(1); MM(1, 1, Br1); __builtin_amdgcn_s_setprio(0);
    BAR();
    // p8: Q(1,0); stage buf1.B h1; certify buf0 ready for next iter
    stageB(1, 1, t1n);
    BAR();
    __builtin_amdgcn_s_setprio(1); MM(1, 0, Br0); __builtin_amdgcn_s_setprio(0);
    VMC(4);  // completes p3..p6 => buf0 fully staged; p7p8 in flight
    BAR();
  }
  VMC(0);  // drain tail junk stages before LDS teardown

  // Epilogue: C layout col=lane&15, row=(lane>>4)*4+reg (16x16x32 bf16 C/D).
  // Split store: col < Nsplit -> C, [Nsplit, Nsplit+N2) -> C2, else dropped.
  const int crow = l4 * 4;
#pragma unroll
  for (int f = 0; f < 8; f++) {
#pragma unroll
    for (int g = 0; g < 4; g++) {
      const int col = n0 + wn * 64 + g * 16 + r15;
      if (col < Nsplit) {
#pragma unroll
        for (int r = 0; r < 4; r++) {
          const size_t row = (size_t)(m0 + wm * 128 + f * 16 + crow + r);
          if (OUT_BF16)
            ((__hip_bfloat16*)C)[row * ldc + col] =
                __float2bfloat16(acc[f][g][r]);
          else
            ((float*)C)[row * ldc + col] = acc[f][g][r];
        }
      } else if (col - Nsplit < N2) {
        const int c2 = col - Nsplit;
#pragma unroll
        for (int r = 0; r < 4; r++) {
          const size_t row = (size_t)(m0 + wm * 128 + f * 16 + crow + r);
          if (OUT_BF16)
            ((__hip_bfloat16*)C2)[row * ldc2 + c2] =
                __float2bfloat16(acc[f][g][r]);
          else
            ((float*)C2)[row * ldc2 + c2] = acc[f][g][r];
        }
      }
    }
  }
}

// -------------------- weight transpose + cast ------------------------------
__global__ __launch_bounds__(256) void transpose_cast(
    const float* __restrict__ in, __hip_bfloat16* __restrict__ out, int K,
    int N) {
  __shared__ float tile[32][33];
  const int n0 = blockIdx.x * 32, k0 = blockIdx.y * 32;
  const int tx = threadIdx.x & 31, ty = threadIdx.x >> 5;
#pragma unroll
  for (int r = 0; r < 32; r += 8) {
    const int k = k0 + ty + r, n = n0 + tx;
    tile[ty + r][tx] = (n < N) ? in[(size_t)k * N + n] : 0.f;
  }
  __syncthreads();
#pragma unroll
  for (int r = 0; r < 32; r += 8) {
    const int n = n0 + ty + r, k = k0 + tx;
    out[(size_t)n * K + k] = __float2bfloat16(tile[tx][ty + r]);
  }
}

// -------------------- x cast ----------------------------------------------
__global__ __launch_bounds__(256) void cast_f32_bf16(
    const float* __restrict__ in, __hip_bfloat16* __restrict__ out) {
  const size_t i = ((size_t)blockIdx.x * 256 + threadIdx.x) * 4;
  const float4 v = *(const float4*)(in + i);
  out[i + 0] = __float2bfloat16(v.x);
  out[i + 1] = __float2bfloat16(v.y);
  out[i + 2] = __float2bfloat16(v.z);
  out[i + 3] = __float2bfloat16(v.w);
}

// -------------------- RMSNorm (bf16 in-place, short8 vectorized) -----------
__global__ __launch_bounds__(256) void rmsnorm_bf16(
    __hip_bfloat16* __restrict__ x, const float* __restrict__ w, int ncols,
    int stride) {
  __hip_bfloat16* xr = x + (size_t)blockIdx.x * stride;
  float ss = 0.f;
  for (int c = threadIdx.x * 8; c < ncols; c += 2048) {
    const short8 v = *(const short8*)(xr + c);
#pragma unroll
    for (int k = 0; k < 8; k++) {
      const float f = bfbits2f((unsigned short)v[k]);
      ss += f * f;
    }
  }
#pragma unroll
  for (int off = 32; off > 0; off >>= 1) ss += __shfl_down(ss, off);
  __shared__ float wsum[4];
  __shared__ float scale_sh;
  const int wv = threadIdx.x >> 6, lane = threadIdx.x & 63;
  if (lane == 0) wsum[wv] = ss;
  __syncthreads();
  if (threadIdx.x == 0) {
    const float tot = wsum[0] + wsum[1] + wsum[2] + wsum[3];
    scale_sh = rsqrtf(tot / (float)ncols + 1e-6f);
  }
  __syncthreads();
  const float scale = scale_sh;
  for (int c = threadIdx.x * 8; c < ncols; c += 2048) {
    const short8 v = *(const short8*)(xr + c);
    short8 o;
#pragma unroll
    for (int k = 0; k < 8; k++) {
      float f = bfbits2f((unsigned short)v[k]) * scale;
      if (w) f *= w[c + k];
      const __hip_bfloat16 b = __float2bfloat16(f);
      o[k] = *(const short*)&b;
    }
    *(short8*)(xr + c) = o;
  }
}

// -------------------- RoPE cos/sin table (double math, once per (pos,i)) ---
// tab[p][i] = (cos, sin) of ((p + start_pos) * 10000^(-i/32)), p in [0,4096).
__global__ __launch_bounds__(256) void build_rope_tab(
    float2* __restrict__ tab, const int* __restrict__ start_pos_p) {
  const int idx = blockIdx.x * 256 + threadIdx.x;  // 4096*32
  const int i = idx & 31;
  const int p = idx >> 5;
  const int pos = p + start_pos_p[0];
  const double theta = pow(10000.0, -(double)i / 32.0);
  const double ang = (double)pos * theta;
  tab[idx] = make_float2((float)cos(ang), (float)sin(ang));
}

// -------------------- RoPE on q (bug-compatible positions, table) ----------
__global__ __launch_bounds__(256) void rope_q_bf16(
    __hip_bfloat16* __restrict__ q, const float2* __restrict__ tab, int t0) {
  const int idx = blockIdx.x * 256 + threadIdx.x;  // Tc*16*32
  const int i = idx & 31;
  const int th = idx >> 5;
  const int t = th >> 4;
  const int h = th & 15;
  const int s_idx = (t0 + t) & 4095;
  const int p = (s_idx * 16 + h) & 4095;
  const float2 cs = tab[p * 32 + i];
  const float c = cs.x, s = cs.y;
  __hip_bfloat16* base = q + (size_t)t * 3072 + h * 192 + 128;
  const float x1 = __bfloat162float(base[i]);
  const float x2 = __bfloat162float(base[i + 32]);
  base[i] = __float2bfloat16(x1 * c - x2 * s);
  base[i + 32] = __float2bfloat16(x2 * c + x1 * s);
}

// -------------------- RoPE on k_pe (pos = start_pos -> table row 0) --------
__global__ __launch_bounds__(256) void rope_kpe_bf16(
    __hip_bfloat16* __restrict__ kv, const float2* __restrict__ tab) {
  const int idx = blockIdx.x * 256 + threadIdx.x;  // Tc*32
  const int i = idx & 31;
  const int t = idx >> 5;
  const float2 cs = tab[i];
  const float c = cs.x, s = cs.y;
  __hip_bfloat16* base = kv + (size_t)t * 576 + 512;
  const float x1 = __bfloat162float(base[i]);
  const float x2 = __bfloat162float(base[i + 32]);
  base[i] = __float2bfloat16(x1 * c - x2 * s);
  base[i + 32] = __float2bfloat16(x2 * c + x1 * s);
}

// -------------------- wave-per-token attention -----------------------------
__global__ __launch_bounds__(256) void attn_wave_token(
    const __hip_bfloat16* __restrict__ q,     // [T][16][192]
    const __hip_bfloat16* __restrict__ kvup,  // [T][16][256] (k_nope|v)
    const __hip_bfloat16* __restrict__ kv,    // [T][576], k_pe at +512
    __hip_bfloat16* __restrict__ ctx) {       // [T][16][128]
  __shared__ __hip_bfloat16 sq[4][16 * 200];
  __shared__ __hip_bfloat16 su[4][16 * 264];
  __shared__ __hip_bfloat16 skpe[4][64];
  __shared__ float sp[4][16][16];
  const int tid = threadIdx.x;
  const int w = tid >> 6;
  const int lane = tid & 63;
  const int t = blockIdx.x * 4 + w;

  const __hip_bfloat16* qb = q + (size_t)t * 3072;
  const __hip_bfloat16* ub = kvup + (size_t)t * 4096;
#pragma unroll
  for (int i = 0; i < 6; i++) {
    const int u = lane + 64 * i;  // u < 384
    const int row = u / 24;
    *(short8*)(&sq[w][u * 8 + row * 8]) = *(const short8*)(qb + u * 8);
  }
#pragma unroll
  for (int i = 0; i < 8; i++) {
    const int u = lane + 64 * i;  // u < 512
    const int row = u >> 5;
    *(short8*)(&su[w][u * 8 + row * 8]) = *(const short8*)(ub + u * 8);
  }
  if (lane < 8)
    *(short8*)(&skpe[w][lane * 8]) =
        *(const short8*)(kv + (size_t)t * 576 + 512 + lane * 8);
  __syncthreads();

  const int qh = lane >> 2;
  const int khb = lane & 3;
  float s[4] = {0.f, 0.f, 0.f, 0.f};
#pragma unroll
  for (int c = 0; c < 128; c += 8) {
    const short8 qv = *(const short8*)(&sq[w][qh * 200 + c]);
    float qf[8];
#pragma unroll
    for (int k = 0; k < 8; k++) qf[k] = bfbits2f((unsigned short)qv[k]);
#pragma unroll
    for (int p = 0; p < 4; p++) {
      const short8 kvv = *(const short8*)(&su[w][(khb + 4 * p) * 264 + c]);
#pragma unroll
      for (int k = 0; k < 8; k++)
        s[p] += qf[k] * bfbits2f((unsigned short)kvv[k]);
    }
  }
#pragma unroll
  for (int c = 0; c < 64; c += 8) {
    const short8 qv = *(const short8*)(&sq[w][qh * 200 + 128 + c]);
    const short8 kvv = *(const short8*)(&skpe[w][c]);
#pragma unroll
    for (int k = 0; k < 8; k++) {
      const float prod =
          bfbits2f((unsigned short)qv[k]) * bfbits2f((unsigned short)kvv[k]);
#pragma unroll
      for (int p = 0; p < 4; p++) s[p] += prod;
    }
  }
  const float scale = 0.07216878364870323f;  // 1/sqrt(192)
#pragma unroll
  for (int p = 0; p < 4; p++) s[p] *= scale;

  float mx = fmaxf(fmaxf(s[0], s[1]), fmaxf(s[2], s[3]));
  mx = fmaxf(mx, __shfl_xor(mx, 1));
  mx = fmaxf(mx, __shfl_xor(mx, 2));
  float e[4], sum = 0.f;
#pragma unroll
  for (int p = 0; p < 4; p++) {
    e[p] = expf(s[p] - mx);
    sum += e[p];
  }
  sum += __shfl_xor(sum, 1);
  sum += __shfl_xor(sum, 2);
  const float inv = 1.0f / sum;
#pragma unroll
  for (int p = 0; p < 4; p++) sp[w][qh][khb + 4 * p] = e[p] * inv;
  __syncthreads();

  const int d0 = (lane & 31) * 4;
  float vreg[16][4];
#pragma unroll
  for (int j = 0; j < 16; j++) {
    const short4x v4 = *(const short4x*)(&su[w][j * 264 + 128 + d0]);
#pragma unroll
    for (int k = 0; k < 4; k++) vreg[j][k] = bfbits2f((unsigned short)v4[k]);
  }
  const int hb = (lane >> 5) * 8;
  __hip_bfloat16* cb = ctx + (size_t)t * 2048;
#pragma unroll
  for (int g = 0; g < 8; g++) {
    const int hh = hb + g;
    float o[4] = {0.f, 0.f, 0.f, 0.f};
#pragma unroll
    for (int j4 = 0; j4 < 4; j4++) {
      const float4 p4 = *(const float4*)(&sp[w][hh][j4 * 4]);
      const float pj[4] = {p4.x, p4.y, p4.z, p4.w};
#pragma unroll
      for (int jj = 0; jj < 4; jj++) {
        const int j = j4 * 4 + jj;
#pragma unroll
        for (int k = 0; k < 4; k++) o[k] += pj[jj] * vreg[j][k];
      }
    }
    short4x st;
#pragma unroll
    for (int k = 0; k < 4; k++) {
      const __hip_bfloat16 b = __float2bfloat16(o[k]);
      st[k] = *(const short*)&b;
    }
    *(short4x*)(cb + hh * 128 + d0) = st;
  }
}

// ---------------------------------------------------------------------------
extern "C" void kernel_launch(void* const* d_in, const int* in_sizes, int n_in,
                              void* d_out, int out_size, void* d_ws,
                              size_t ws_size, hipStream_t stream) {
  const float* x = (const float*)d_in[0];          // 16384 x 2048
  const float* wq_a = (const float*)d_in[1];       // 2048 x 1536
  const float* q_norm_w = (const float*)d_in[2];   // 1536
  const float* wq_b = (const float*)d_in[3];       // 1536 x 3072
  const float* wkv_a = (const float*)d_in[4];      // 2048 x 576
  const float* wkv_b = (const float*)d_in[5];      // 512 x 4096
  const float* wo = (const float*)d_in[6];         // 2048 x 2048
  const int* start_pos = (const int*)d_in[7];
  float* out = (float*)d_out;

  const int T = 16384;
  __hip_bfloat16* w0 = (__hip_bfloat16*)d_ws;
  // wq_aT and wkv_aT contiguous: one 2304x2048 Bt for the fused G1+G3.
  __hip_bfloat16* wqkv_aT = w0;                      // 2304 x 2048
  __hip_bfloat16* wq_aT = wqkv_aT;                   // rows 0..1535
  __hip_bfloat16* wkv_aT = wqkv_aT + 1536 * 2048;    // rows 1536..2303 (pad)
  __hip_bfloat16* wq_bT = wqkv_aT + 2304 * 2048;     // 3072 x 1536
  __hip_bfloat16* wkv_bT = wq_bT + 3072 * 1536;      // 4096 x 512
  __hip_bfloat16* woT = wkv_bT + 4096 * 512;         // 2048 x 2048
  float2* rope_tab = (float2*)(woT + 2048 * 2048);   // 4096 x 32 float2 (1MB)
  __hip_bfloat16* chunk0 = (__hip_bfloat16*)(rope_tab + 4096 * 32);
  const size_t w_bytes = (size_t)((char*)chunk0 - (char*)w0);

  const size_t per_tok = 11840 * sizeof(__hip_bfloat16);
  int Tc = T;
  while (Tc > 256 && w_bytes + (size_t)Tc * per_tok > ws_size) Tc >>= 1;

  __hip_bfloat16* xb = chunk0;                       // Tc x 2048
  __hip_bfloat16* q_buf = xb + (size_t)Tc * 2048;    // Tc x 3072
  __hip_bfloat16* kvup = q_buf + (size_t)Tc * 3072;  // Tc x 4096
  __hip_bfloat16* cbuf = kvup + (size_t)Tc * 4096;   // Tc x 2048
  __hip_bfloat16* kv = cbuf + (size_t)Tc * 2048;     // Tc x 576

  dim3 blk(256);
  dim3 blk512(512);

  transpose_cast<<<dim3(1536 / 32, 2048 / 32), blk, 0, stream>>>(wq_a, wq_aT,
                                                                 2048, 1536);
  transpose_cast<<<dim3(768 / 32, 2048 / 32), blk, 0, stream>>>(wkv_a, wkv_aT,
                                                                2048, 576);
  transpose_cast<<<dim3(3072 / 32, 1536 / 32), blk, 0, stream>>>(wq_b, wq_bT,
                                                                 1536, 3072);
  transpose_cast<<<dim3(4096 / 32, 512 / 32), blk, 0, stream>>>(wkv_b, wkv_bT,
                                                                512, 4096);
  transpose_cast<<<dim3(2048 / 32, 2048 / 32), blk, 0, stream>>>(wo, woT, 2048,
                                                                 2048);
  build_rope_tab<<<(4096 * 32) / 256, blk, 0, stream>>>(rope_tab, start_pos);

  const int nby = Tc / 256;
  for (int t0 = 0; t0 < T; t0 += Tc) {
    cast_f32_bf16<<<(Tc * 2048) / 1024, blk, 0, stream>>>(
        x + (size_t)t0 * 2048, xb);
    // G1+G3 fused: [q_lora | kv] = xb @ [wq_a | wkv_a]^T
    // cols 0..1535 -> cbuf (ld 1536); 1536..2111 -> kv (ld 576); rest dropped
    gemm256_8ph<true><<<dim3(9 * nby), blk512, 0, stream>>>(
        xb, wqkv_aT, cbuf, 1536, 1536, kv, 576, 576, 2048, 2048, 9);
    rmsnorm_bf16<<<Tc, blk, 0, stream>>>(cbuf, q_norm_w, 1536, 1536);
    rope_kpe_bf16<<<(Tc * 32) / 256, blk, 0, stream>>>(kv, rope_tab);
    rmsnorm_bf16<<<Tc, blk, 0, stream>>>(kv, nullptr, 512, 576);
    // G2: q = q_lora @ wq_b^T
    gemm256_8ph<true><<<dim3(12 * nby), blk512, 0, stream>>>(
        cbuf, wq_bT, q_buf, 3072, 3072, nullptr, 0, 0, 1536, 1536, 12);
    rope_q_bf16<<<(Tc * 16 * 32) / 256, blk, 0, stream>>>(q_buf, rope_tab, t0);
    // G4: kvup = kvn @ wkv_b^T (A ld 576, K=512)
    gemm256_8ph<true><<<dim3(16 * nby), blk512, 0, stream>>>(
        kv, wkv_bT, kvup, 4096, 4096, nullptr, 0, 0, 512, 576, 16);
    // attention -> ctx (reuses cbuf)
    attn_wave_token<<<Tc / 4, blk, 0, stream>>>(q_buf, kvup, kv, cbuf);
    // G5: out = ctx @ wo^T (fp32 out)
    gemm256_8ph<false><<<dim3(8 * nby), blk512, 0, stream>>>(
        cbuf, woT, out + (size_t)t0 * 2048, 2048, 2048, nullptr, 0, 0, 2048,
        2048, 8);
  }
}

// Round 7
// 951.820 us; speedup vs baseline: 1.0818x; 1.0035x over previous
//
#include <hip/hip_runtime.h>
#include <hip/hip_bf16.h>
#include <math.h>

// ---------------------------------------------------------------------------
// MLA forward. GEMMs: 256x256 8-phase MFMA schedule (T2 swizzle + counted
// vmcnt + setprio), 16x16x32 MFMA — round-2/round-4 verified schedule.
// RoPE via precomputed cos/sin table. G1+G3 fused. rope_kpe+rmsnorm fused.
// NOTE: one-phase-ahead ds_read pipelining was tried (r5/r6) and is
// retired: cross-wave staging race (vmcnt is per-wave; reads before the
// certifying barrier see other waves' in-flight loads) + VGPR overflow.
// ---------------------------------------------------------------------------

typedef __attribute__((ext_vector_type(8))) short short8;
typedef __attribute__((ext_vector_type(4))) short short4x;
typedef __attribute__((ext_vector_type(4))) float floatx4;

__device__ inline float bfbits2f(unsigned short u) {
  union { unsigned int i; float f; } c;
  c.i = ((unsigned int)u) << 16;
  return c.f;
}

#define FENCE() asm volatile("" ::: "memory")
#define BAR()                       \
  do {                              \
    FENCE();                        \
    __builtin_amdgcn_s_barrier();   \
    FENCE();                        \
  } while (0)
#define LGKM0()                                       \
  do {                                                \
    asm volatile("s_waitcnt lgkmcnt(0)" ::: "memory");\
    __builtin_amdgcn_sched_barrier(0);                \
  } while (0)
#define VMC(n) asm volatile("s_waitcnt vmcnt(" #n ")" ::: "memory")

// -------------------- 256x256 8-phase bf16 GEMM, B transposed --------------
// C[M][*] = A[M][K] (bf16, ld lda) x Bt[Npad][K] (bf16, ld K)^T
// Columns < Nsplit -> C (ld ldc); columns in [Nsplit, Nsplit+N2) -> C2
// (ld ldc2, col-Nsplit); other columns dropped.
// M % 256 == 0, Npad % 256 == 0, K % 128 == 0.
// 512 threads = 8 waves (2M x 4N); per-wave output 128x64 (8x4 frags of
// 16x16x32); BK=64, 2 K-tiles per iteration, 8 phases/iter.
// LDS: 2 bufs x (A 256x64 + B 256x64) bf16 = 128 KB -> 1 block/CU.
// Swizzle: within each 128B row, 16B slot ^= (row&7); applied on the GLOBAL
// source of global_load_lds (linear LDS dest) and on the ds_read side.
#define RD_A(cb, qm)                                                     \
  {                                                                      \
    _Pragma("unroll") for (int f_ = 0; f_ < 4; f_++) {                   \
      _Pragma("unroll") for (int ks_ = 0; ks_ < 2; ks_++) {              \
        Ar[f_][ks_] = *(const short8*)(ldsb + (cb) * 65536 +             \
            (wm * 128 + (qm) * 64 + f_ * 16 + r15) * 128 +               \
            (((ks_ * 4 + l4) ^ lx) << 4));                               \
      }                                                                  \
    }                                                                    \
  }

#define RD_B(cb, qn, Brg)                                                \
  {                                                                      \
    _Pragma("unroll") for (int g_ = 0; g_ < 2; g_++) {                   \
      _Pragma("unroll") for (int ks_ = 0; ks_ < 2; ks_++) {              \
        Brg[g_][ks_] = *(const short8*)(ldsb + (cb) * 65536 + 32768 +    \
            (wn * 64 + (qn) * 32 + g_ * 16 + r15) * 128 +                \
            (((ks_ * 4 + l4) ^ lx) << 4));                               \
      }                                                                  \
    }                                                                    \
  }

#define MM(qm, qn, B)                                                    \
  {                                                                      \
    _Pragma("unroll") for (int f_ = 0; f_ < 4; f_++) {                   \
      _Pragma("unroll") for (int g_ = 0; g_ < 2; g_++) {                 \
        acc[(qm) * 4 + f_][(qn) * 2 + g_] =                              \
            __builtin_amdgcn_mfma_f32_16x16x32_bf16(                     \
                Ar[f_][0], B[g_][0], acc[(qm) * 4 + f_][(qn) * 2 + g_],  \
                0, 0, 0);                                                \
        acc[(qm) * 4 + f_][(qn) * 2 + g_] =                              \
            __builtin_amdgcn_mfma_f32_16x16x32_bf16(                     \
                Ar[f_][1], B[g_][1], acc[(qm) * 4 + f_][(qn) * 2 + g_],  \
                0, 0, 0);                                                \
      }                                                                  \
    }                                                                    \
  }

template <bool OUT_BF16>
__global__ __launch_bounds__(512, 2) void gemm256_8ph(
    const __hip_bfloat16* __restrict__ A, const __hip_bfloat16* __restrict__ Bt,
    void* __restrict__ C, int Nsplit, int ldc,
    void* __restrict__ C2, int ldc2, int N2,
    int K, int lda, int nbx) {
  __shared__ __hip_bfloat16 lds[2][2][16384];  // [buf][A|B][256*64]
  const int tid = threadIdx.x;
  const int lane = tid & 63;
  const int wave = tid >> 6;
  const int wm = wave >> 2;  // 0..1
  const int wn = wave & 3;   // 0..3
  const int r15 = lane & 15;
  const int l4 = lane >> 4;
  const int lx = lane & 7;

  // XCD-chunked block swizzle (bijective when gridDim %8 == 0).
  const int nwg = gridDim.x;
  int wg = blockIdx.x;
  if ((nwg & 7) == 0) wg = (wg & 7) * (nwg >> 3) + (wg >> 3);
  const int by = wg / nbx;
  const int bx = wg - by * nbx;
  const int m0 = by * 256;
  const int n0 = bx * 256;

  // Staging: thread covers linear units u = i*512+tid of a 128x64 half-tile.
  // LDS dest linear (u*16B); global source pre-swizzled: slot ^= row&7.
  const int lr0 = tid >> 3;                 // local row, i=0 (i=1 adds 64)
  const int sg0 = (tid & 7) ^ (lr0 & 7);    // swizzled source slot
  const __hip_bfloat16* aSrc = A + (size_t)(m0 + lr0) * lda + sg0 * 8;
  const __hip_bfloat16* bSrc = Bt + (size_t)(n0 + lr0) * (size_t)K + sg0 * 8;

  auto stageA = [&](int cb, int h, int kt) {
#pragma unroll
    for (int i = 0; i < 2; i++) {
      const __hip_bfloat16* src = aSrc + (size_t)((h * 128 + i * 64) * lda + kt);
      __builtin_amdgcn_global_load_lds(
          (const __attribute__((address_space(1))) void*)src,
          (__attribute__((address_space(3))) void*)&lds[cb][0]
              [h * 8192 + (i * 512 + tid) * 8],
          16, 0, 0);
    }
  };
  auto stageB = [&](int cb, int h, int kt) {
#pragma unroll
    for (int i = 0; i < 2; i++) {
      const __hip_bfloat16* src = bSrc + (size_t)((h * 128 + i * 64) * K + kt);
      __builtin_amdgcn_global_load_lds(
          (const __attribute__((address_space(1))) void*)src,
          (__attribute__((address_space(3))) void*)&lds[cb][1]
              [h * 8192 + (i * 512 + tid) * 8],
          16, 0, 0);
    }
  };

  floatx4 acc[8][4] = {};
  short8 Ar[4][2], Br0[2][2], Br1[2][2];
  const char* ldsb = (const char*)&lds[0][0][0];

  // Prologue: buf0 = tile0 (B then A), buf1.B = tile1. 12 loads/thread.
  stageB(0, 0, 0); stageB(0, 1, 0);
  stageA(0, 0, 0); stageA(0, 1, 0);
  stageB(1, 0, 64); stageB(1, 1, 64);
  VMC(4);  // buf0 complete; buf1.B (4 loads) stays in flight
  BAR();

  const int niter = K >> 7;  // 2 K-tiles per iteration
#pragma unroll 1
  for (int it = 0; it < niter; ++it) {
    const int ktc = it * 128;
    const int kt1 = ktc + 64;                          // tile for phases 5-8
    const int t0n = (ktc + 128 < K) ? ktc + 128 : 0;   // buf0 next (clamped)
    const int t1n = (ktc + 192 < K) ? ktc + 192 : 0;   // buf1 next (clamped)

    // p1: compute buf0 Q(0,0); stage buf1.A h0 (this iter's tile1)
    RD_A(0, 0); RD_B(0, 0, Br0);
    stageA(1, 0, kt1);
    BAR(); LGKM0();
    __builtin_amdgcn_s_setprio(1); MM(0, 0, Br0); __builtin_amdgcn_s_setprio(0);
    BAR();
    // p2: Q(0,1); stage buf1.A h1
    RD_B(0, 1, Br1);
    stageA(1, 1, kt1);
    BAR(); LGKM0();
    __builtin_amdgcn_s_setprio(1); MM(0, 1, Br1); __builtin_amdgcn_s_setprio(0);
    BAR();
    // p3: Q(1,1); stage buf0.B h0 (next iter) — buf0.B free after p2
    RD_A(0, 1);
    stageB(0, 0, t0n);
    BAR(); LGKM0();
    __builtin_amdgcn_s_setprio(1); MM(1, 1, Br1); __builtin_amdgcn_s_setprio(0);
    BAR();
    // p4: Q(1,0) (regs only); stage buf0.B h1; certify buf1 ready
    stageB(0, 1, t0n);
    BAR();
    __builtin_amdgcn_s_setprio(1); MM(1, 0, Br0); __builtin_amdgcn_s_setprio(0);
    VMC(4);  // completes prologue-leftover + p1p2 => buf1 fully staged
    BAR();
    // p5: compute buf1 Q(0,0); stage buf0.A h0 — buf0.A free after p3
    RD_A(1, 0); RD_B(1, 0, Br0);
    stageA(0, 0, t0n);
    BAR(); LGKM0();
    __builtin_amdgcn_s_setprio(1); MM(0, 0, Br0); __builtin_amdgcn_s_setprio(0);
    BAR();
    // p6: Q(0,1); stage buf0.A h1
    RD_B(1, 1, Br1);
    stageA(0, 1, t0n);
    BAR(); LGKM0();
    __builtin_amdgcn_s_setprio(1); MM(0, 1, Br1); __builtin_amdgcn_s_setprio(0);
    BAR();
    // p7: Q(1,1); stage buf1.B h0 — buf1.B free after p6
    RD_A(1, 1);
    stageB(1, 0, t1n);
    BAR(); LGKM0();
    __builtin_amdgcn_s_setprio(1); MM(1, 1, Br1); __builtin_amdgcn_s_setprio(0);
    BAR();
    // p8: Q(1,0); stage buf1.B h1; certify buf0 ready for next iter
    stageB(1, 1, t1n);
    BAR();
    __builtin_amdgcn_s_setprio(1); MM(1, 0, Br0); __builtin_amdgcn_s_setprio(0);
    VMC(4);  // completes p3..p6 => buf0 fully staged; p7p8 in flight
    BAR();
  }
  VMC(0);  // drain tail junk stages before LDS teardown

  // Epilogue: C layout col=lane&15, row=(lane>>4)*4+reg (16x16x32 bf16 C/D).
  // Split store: col < Nsplit -> C, [Nsplit, Nsplit+N2) -> C2, else dropped.
  const int crow = l4 * 4;
#pragma unroll
  for (int f = 0; f < 8; f++) {
#pragma unroll
    for (int g = 0; g < 4; g++) {
      const int col = n0 + wn * 64 + g * 16 + r15;
      if (col < Nsplit) {
#pragma unroll
        for (int r = 0; r < 4; r++) {
          const size_t row = (size_t)(m0 + wm * 128 + f * 16 + crow + r);
          if (OUT_BF16)
            ((__hip_bfloat16*)C)[row * ldc + col] =
                __float2bfloat16(acc[f][g][r]);
          else
            ((float*)C)[row * ldc + col] = acc[f][g][r];
        }
      } else if (col - Nsplit < N2) {
        const int c2 = col - Nsplit;
#pragma unroll
        for (int r = 0; r < 4; r++) {
          const size_t row = (size_t)(m0 + wm * 128 + f * 16 + crow + r);
          if (OUT_BF16)
            ((__hip_bfloat16*)C2)[row * ldc2 + c2] =
                __float2bfloat16(acc[f][g][r]);
          else
            ((float*)C2)[row * ldc2 + c2] = acc[f][g][r];
        }
      }
    }
  }
}

// -------------------- weight transpose + cast ------------------------------
__global__ __launch_bounds__(256) void transpose_cast(
    const float* __restrict__ in, __hip_bfloat16* __restrict__ out, int K,
    int N) {
  __shared__ float tile[32][33];
  const int n0 = blockIdx.x * 32, k0 = blockIdx.y * 32;
  const int tx = threadIdx.x & 31, ty = threadIdx.x >> 5;
#pragma unroll
  for (int r = 0; r < 32; r += 8) {
    const int k = k0 + ty + r, n = n0 + tx;
    tile[ty + r][tx] = (n < N) ? in[(size_t)k * N + n] : 0.f;
  }
  __syncthreads();
#pragma unroll
  for (int r = 0; r < 32; r += 8) {
    const int n = n0 + ty + r, k = k0 + tx;
    out[(size_t)n * K + k] = __float2bfloat16(tile[tx][ty + r]);
  }
}

// -------------------- x cast (8 elems/thread, packed short8 store) ---------
__global__ __launch_bounds__(256) void cast_f32_bf16(
    const float* __restrict__ in, __hip_bfloat16* __restrict__ out) {
  const size_t i = ((size_t)blockIdx.x * 256 + threadIdx.x) * 8;
  const float4 v0 = *(const float4*)(in + i);
  const float4 v1 = *(const float4*)(in + i + 4);
  const float f[8] = {v0.x, v0.y, v0.z, v0.w, v1.x, v1.y, v1.z, v1.w};
  short8 o;
#pragma unroll
  for (int k = 0; k < 8; k++) {
    const __hip_bfloat16 b = __float2bfloat16(f[k]);
    o[k] = *(const short*)&b;
  }
  *(short8*)(out + i) = o;
}

// -------------------- RMSNorm (bf16 in-place, short8 vectorized) -----------
__global__ __launch_bounds__(256) void rmsnorm_bf16(
    __hip_bfloat16* __restrict__ x, const float* __restrict__ w, int ncols,
    int stride) {
  __hip_bfloat16* xr = x + (size_t)blockIdx.x * stride;
  float ss = 0.f;
  for (int c = threadIdx.x * 8; c < ncols; c += 2048) {
    const short8 v = *(const short8*)(xr + c);
#pragma unroll
    for (int k = 0; k < 8; k++) {
      const float f = bfbits2f((unsigned short)v[k]);
      ss += f * f;
    }
  }
#pragma unroll
  for (int off = 32; off > 0; off >>= 1) ss += __shfl_down(ss, off);
  __shared__ float wsum[4];
  __shared__ float scale_sh;
  const int wv = threadIdx.x >> 6, lane = threadIdx.x & 63;
  if (lane == 0) wsum[wv] = ss;
  __syncthreads();
  if (threadIdx.x == 0) {
    const float tot = wsum[0] + wsum[1] + wsum[2] + wsum[3];
    scale_sh = rsqrtf(tot / (float)ncols + 1e-6f);
  }
  __syncthreads();
  const float scale = scale_sh;
  for (int c = threadIdx.x * 8; c < ncols; c += 2048) {
    const short8 v = *(const short8*)(xr + c);
    short8 o;
#pragma unroll
    for (int k = 0; k < 8; k++) {
      float f = bfbits2f((unsigned short)v[k]) * scale;
      if (w) f *= w[c + k];
      const __hip_bfloat16 b = __float2bfloat16(f);
      o[k] = *(const short*)&b;
    }
    *(short8*)(xr + c) = o;
  }
}

// -------------------- RoPE cos/sin table (double math, once per (pos,i)) ---
// tab[p][i] = (cos, sin) of ((p + start_pos) * 10000^(-i/32)), p in [0,4096).
__global__ __launch_bounds__(256) void build_rope_tab(
    float2* __restrict__ tab, const int* __restrict__ start_pos_p) {
  const int idx = blockIdx.x * 256 + threadIdx.x;  // 4096*32
  const int i = idx & 31;
  const int p = idx >> 5;
  const int pos = p + start_pos_p[0];
  const double theta = pow(10000.0, -(double)i / 32.0);
  const double ang = (double)pos * theta;
  tab[idx] = make_float2((float)cos(ang), (float)sin(ang));
}

// -------------------- RoPE on q (bug-compatible positions, table) ----------
__global__ __launch_bounds__(256) void rope_q_bf16(
    __hip_bfloat16* __restrict__ q, const float2* __restrict__ tab, int t0) {
  const int idx = blockIdx.x * 256 + threadIdx.x;  // Tc*16*32
  const int i = idx & 31;
  const int th = idx >> 5;
  const int t = th >> 4;
  const int h = th & 15;
  const int s_idx = (t0 + t) & 4095;
  const int p = (s_idx * 16 + h) & 4095;
  const float2 cs = tab[p * 32 + i];
  const float c = cs.x, s = cs.y;
  __hip_bfloat16* base = q + (size_t)t * 3072 + h * 192 + 128;
  const float x1 = __bfloat162float(base[i]);
  const float x2 = __bfloat162float(base[i + 32]);
  base[i] = __float2bfloat16(x1 * c - x2 * s);
  base[i + 32] = __float2bfloat16(x2 * c + x1 * s);
}

// -------------------- fused RoPE(k_pe) + RMSNorm(kv_c) ---------------------
// One block per token. Cols 0..511 (kv_c) get RMSNorm; cols 512..575 (k_pe)
// get RoPE with pos=start_pos (table row 0). Disjoint regions: wave 0 does
// the norm, wave 1 lanes 0..31 do the rope pairs. 128 threads.
__global__ __launch_bounds__(128) void rope_rms_kv(
    __hip_bfloat16* __restrict__ kv, const float2* __restrict__ tab) {
  __hip_bfloat16* xr = kv + (size_t)blockIdx.x * 576;
  const int tid = threadIdx.x;
  __shared__ float scale_sh;
  float ss = 0.f;
  short8 v;
  if (tid < 64) {
    v = *(const short8*)(xr + tid * 8);  // 64 threads x 8 = 512 cols
#pragma unroll
    for (int k = 0; k < 8; k++) {
      const float f = bfbits2f((unsigned short)v[k]);
      ss += f * f;
    }
  } else if (tid < 96) {
    const int i = tid - 64;
    const float2 cs = tab[i];
    __hip_bfloat16* base = xr + 512;
    const float x1 = __bfloat162float(base[i]);
    const float x2 = __bfloat162float(base[i + 32]);
    base[i] = __float2bfloat16(x1 * cs.x - x2 * cs.y);
    base[i + 32] = __float2bfloat16(x2 * cs.x + x1 * cs.y);
  }
  // Reduce across wave 0 (wave 1 computes garbage reduce, unused).
#pragma unroll
  for (int off = 32; off > 0; off >>= 1) ss += __shfl_down(ss, off);
  if (tid == 0) scale_sh = rsqrtf(ss / 512.f + 1e-6f);
  __syncthreads();
  if (tid < 64) {
    const float scale = scale_sh;
    short8 o;
#pragma unroll
    for (int k = 0; k < 8; k++) {
      const __hip_bfloat16 b =
          __float2bfloat16(bfbits2f((unsigned short)v[k]) * scale);
      o[k] = *(const short*)&b;
    }
    *(short8*)(xr + tid * 8) = o;
  }
}

// -------------------- wave-per-token attention -----------------------------
__global__ __launch_bounds__(256) void attn_wave_token(
    const __hip_bfloat16* __restrict__ q,     // [T][16][192]
    const __hip_bfloat16* __restrict__ kvup,  // [T][16][256] (k_nope|v)
    const __hip_bfloat16* __restrict__ kv,    // [T][576], k_pe at +512
    __hip_bfloat16* __restrict__ ctx) {       // [T][16][128]
  __shared__ __hip_bfloat16 sq[4][16 * 200];
  __shared__ __hip_bfloat16 su[4][16 * 264];
  __shared__ __hip_bfloat16 skpe[4][64];
  __shared__ float sp[4][16][16];
  const int tid = threadIdx.x;
  const int w = tid >> 6;
  const int lane = tid & 63;
  const int t = blockIdx.x * 4 + w;

  const __hip_bfloat16* qb = q + (size_t)t * 3072;
  const __hip_bfloat16* ub = kvup + (size_t)t * 4096;
#pragma unroll
  for (int i = 0; i < 6; i++) {
    const int u = lane + 64 * i;  // u < 384
    const int row = u / 24;
    *(short8*)(&sq[w][u * 8 + row * 8]) = *(const short8*)(qb + u * 8);
  }
#pragma unroll
  for (int i = 0; i < 8; i++) {
    const int u = lane + 64 * i;  // u < 512
    const int row = u >> 5;
    *(short8*)(&su[w][u * 8 + row * 8]) = *(const short8*)(ub + u * 8);
  }
  if (lane < 8)
    *(short8*)(&skpe[w][lane * 8]) =
        *(const short8*)(kv + (size_t)t * 576 + 512 + lane * 8);
  __syncthreads();

  const int qh = lane >> 2;
  const int khb = lane & 3;
  float s[4] = {0.f, 0.f, 0.f, 0.f};
#pragma unroll
  for (int c = 0; c < 128; c += 8) {
    const short8 qv = *(const short8*)(&sq[w][qh * 200 + c]);
    float qf[8];
#pragma unroll
    for (int k = 0; k < 8; k++) qf[k] = bfbits2f((unsigned short)qv[k]);
#pragma unroll
    for (int p = 0; p < 4; p++) {
      const short8 kvv = *(const short8*)(&su[w][(khb + 4 * p) * 264 + c]);
#pragma unroll
      for (int k = 0; k < 8; k++)
        s[p] += qf[k] * bfbits2f((unsigned short)kvv[k]);
    }
  }
#pragma unroll
  for (int c = 0; c < 64; c += 8) {
    const short8 qv = *(const short8*)(&sq[w][qh * 200 + 128 + c]);
    const short8 kvv = *(const short8*)(&skpe[w][c]);
#pragma unroll
    for (int k = 0; k < 8; k++) {
      const float prod =
          bfbits2f((unsigned short)qv[k]) * bfbits2f((unsigned short)kvv[k]);
#pragma unroll
      for (int p = 0; p < 4; p++) s[p] += prod;
    }
  }
  const float scale = 0.07216878364870323f;  // 1/sqrt(192)
#pragma unroll
  for (int p = 0; p < 4; p++) s[p] *= scale;

  float mx = fmaxf(fmaxf(s[0], s[1]), fmaxf(s[2], s[3]));
  mx = fmaxf(mx, __shfl_xor(mx, 1));
  mx = fmaxf(mx, __shfl_xor(mx, 2));
  float e[4], sum = 0.f;
#pragma unroll
  for (int p = 0; p < 4; p++) {
    e[p] = expf(s[p] - mx);
    sum += e[p];
  }
  sum += __shfl_xor(sum, 1);
  sum += __shfl_xor(sum, 2);
  const float inv = 1.0f / sum;
#pragma unroll
  for (int p = 0; p < 4; p++) sp[w][qh][khb + 4 * p] = e[p] * inv;
  __syncthreads();

  const int d0 = (lane & 31) * 4;
  float vreg[16][4];
#pragma unroll
  for (int j = 0; j < 16; j++) {
    const short4x v4 = *(const short4x*)(&su[w][j * 264 + 128 + d0]);
#pragma unroll
    for (int k = 0; k < 4; k++) vreg[j][k] = bfbits2f((unsigned short)v4[k]);
  }
  const int hb = (lane >> 5) * 8;
  __hip_bfloat16* cb = ctx + (size_t)t * 2048;
#pragma unroll
  for (int g = 0; g < 8; g++) {
    const int hh = hb + g;
    float o[4] = {0.f, 0.f, 0.f, 0.f};
#pragma unroll
    for (int j4 = 0; j4 < 4; j4++) {
      const float4 p4 = *(const float4*)(&sp[w][hh][j4 * 4]);
      const float pj[4] = {p4.x, p4.y, p4.z, p4.w};
#pragma unroll
      for (int jj = 0; jj < 4; jj++) {
        const int j = j4 * 4 + jj;
#pragma unroll
        for (int k = 0; k < 4; k++) o[k] += pj[jj] * vreg[j][k];
      }
    }
    short4x st;
#pragma unroll
    for (int k = 0; k < 4; k++) {
      const __hip_bfloat16 b = __float2bfloat16(o[k]);
      st[k] = *(const short*)&b;
    }
    *(short4x*)(cb + hh * 128 + d0) = st;
  }
}

// ---------------------------------------------------------------------------
extern "C" void kernel_launch(void* const* d_in, const int* in_sizes, int n_in,
                              void* d_out, int out_size, void* d_ws,
                              size_t ws_size, hipStream_t stream) {
  const float* x = (const float*)d_in[0];          // 16384 x 2048
  const float* wq_a = (const float*)d_in[1];       // 2048 x 1536
  const float* q_norm_w = (const float*)d_in[2];   // 1536
  const float* wq_b = (const float*)d_in[3];       // 1536 x 3072
  const float* wkv_a = (const float*)d_in[4];      // 2048 x 576
  const float* wkv_b = (const float*)d_in[5];      // 512 x 4096
  const float* wo = (const float*)d_in[6];         // 2048 x 2048
  const int* start_pos = (const int*)d_in[7];
  float* out = (float*)d_out;

  const int T = 16384;
  __hip_bfloat16* w0 = (__hip_bfloat16*)d_ws;
  // wq_aT and wkv_aT contiguous: one 2304x2048 Bt for the fused G1+G3.
  __hip_bfloat16* wqkv_aT = w0;                      // 2304 x 2048
  __hip_bfloat16* wq_aT = wqkv_aT;                   // rows 0..1535
  __hip_bfloat16* wkv_aT = wqkv_aT + 1536 * 2048;    // rows 1536..2303 (pad)
  __hip_bfloat16* wq_bT = wqkv_aT + 2304 * 2048;     // 3072 x 1536
  __hip_bfloat16* wkv_bT = wq_bT + 3072 * 1536;      // 4096 x 512
  __hip_bfloat16* woT = wkv_bT + 4096 * 512;         // 2048 x 2048
  float2* rope_tab = (float2*)(woT + 2048 * 2048);   // 4096 x 32 float2 (1MB)
  __hip_bfloat16* chunk0 = (__hip_bfloat16*)(rope_tab + 4096 * 32);
  const size_t w_bytes = (size_t)((char*)chunk0 - (char*)w0);

  const size_t per_tok = 11840 * sizeof(__hip_bfloat16);
  int Tc = T;
  while (Tc > 256 && w_bytes + (size_t)Tc * per_tok > ws_size) Tc >>= 1;

  __hip_bfloat16* xb = chunk0;                       // Tc x 2048
  __hip_bfloat16* q_buf = xb + (size_t)Tc * 2048;    // Tc x 3072
  __hip_bfloat16* kvup = q_buf + (size_t)Tc * 3072;  // Tc x 4096
  __hip_bfloat16* cbuf = kvup + (size_t)Tc * 4096;   // Tc x 2048
  __hip_bfloat16* kv = cbuf + (size_t)Tc * 2048;     // Tc x 576

  dim3 blk(256);
  dim3 blk512(512);

  transpose_cast<<<dim3(1536 / 32, 2048 / 32), blk, 0, stream>>>(wq_a, wq_aT,
                                                                 2048, 1536);
  transpose_cast<<<dim3(768 / 32, 2048 / 32), blk, 0, stream>>>(wkv_a, wkv_aT,
                                                                2048, 576);
  transpose_cast<<<dim3(3072 / 32, 1536 / 32), blk, 0, stream>>>(wq_b, wq_bT,
                                                                 1536, 3072);
  transpose_cast<<<dim3(4096 / 32, 512 / 32), blk, 0, stream>>>(wkv_b, wkv_bT,
                                                                512, 4096);
  transpose_cast<<<dim3(2048 / 32, 2048 / 32), blk, 0, stream>>>(wo, woT, 2048,
                                                                 2048);
  build_rope_tab<<<(4096 * 32) / 256, blk, 0, stream>>>(rope_tab, start_pos);

  const int nby = Tc / 256;
  for (int t0 = 0; t0 < T; t0 += Tc) {
    cast_f32_bf16<<<(Tc * 2048) / 2048, blk, 0, stream>>>(
        x + (size_t)t0 * 2048, xb);
    // G1+G3 fused: [q_lora | kv] = xb @ [wq_a | wkv_a]^T
    // cols 0..1535 -> cbuf (ld 1536); 1536..2111 -> kv (ld 576); rest dropped
    gemm256_8ph<true><<<dim3(9 * nby), blk512, 0, stream>>>(
        xb, wqkv_aT, cbuf, 1536, 1536, kv, 576, 576, 2048, 2048, 9);
    rmsnorm_bf16<<<Tc, blk, 0, stream>>>(cbuf, q_norm_w, 1536, 1536);
    // fused rope(k_pe) + rmsnorm(kv_c)
    rope_rms_kv<<<Tc, dim3(128), 0, stream>>>(kv, rope_tab);
    // G2: q = q_lora @ wq_b^T
    gemm256_8ph<true><<<dim3(12 * nby), blk512, 0, stream>>>(
        cbuf, wq_bT, q_buf, 3072, 3072, nullptr, 0, 0, 1536, 1536, 12);
    rope_q_bf16<<<(Tc * 16 * 32) / 256, blk, 0, stream>>>(q_buf, rope_tab, t0);
    // G4: kvup = kvn @ wkv_b^T (A ld 576, K=512)
    gemm256_8ph<true><<<dim3(16 * nby), blk512, 0, stream>>>(
        kv, wkv_bT, kvup, 4096, 4096, nullptr, 0, 0, 512, 576, 16);
    // attention -> ctx (reuses cbuf)
    attn_wave_token<<<Tc / 4, blk, 0, stream>>>(q_buf, kvup, kv, cbuf);
    // G5: out = ctx @ wo^T (fp32 out)
    gemm256_8ph<false><<<dim3(8 * nby), blk512, 0, stream>>>(
        cbuf, woT, out + (size_t)t0 * 2048, 2048, 2048, nullptr, 0, 0, 2048,
        2048, 8);
  }
}

// Round 8
// 914.213 us; speedup vs baseline: 1.1263x; 1.0411x over previous
//
#include <hip/hip_runtime.h>
#include <hip/hip_bf16.h>
#include <math.h>

// ---------------------------------------------------------------------------
// MLA forward. GEMMs: 256x256 8-phase MFMA schedule (T2 swizzle + counted
// vmcnt + setprio), 16x16x32 MFMA — round-2/round-7 verified schedule.
// RoPE via precomputed cos/sin table. G1+G3 fused. rope_kpe+rmsnorm fused.
// Attention QK^T now on MFMA (same 16x16x32 fragment mapping as the GEMM).
// ---------------------------------------------------------------------------

typedef __attribute__((ext_vector_type(8))) short short8;
typedef __attribute__((ext_vector_type(4))) short short4x;
typedef __attribute__((ext_vector_type(4))) float floatx4;

__device__ inline float bfbits2f(unsigned short u) {
  union { unsigned int i; float f; } c;
  c.i = ((unsigned int)u) << 16;
  return c.f;
}

#define FENCE() asm volatile("" ::: "memory")
#define BAR()                       \
  do {                              \
    FENCE();                        \
    __builtin_amdgcn_s_barrier();   \
    FENCE();                        \
  } while (0)
#define LGKM0()                                       \
  do {                                                \
    asm volatile("s_waitcnt lgkmcnt(0)" ::: "memory");\
    __builtin_amdgcn_sched_barrier(0);                \
  } while (0)
#define VMC(n) asm volatile("s_waitcnt vmcnt(" #n ")" ::: "memory")

// -------------------- 256x256 8-phase bf16 GEMM, B transposed --------------
// (structure identical to round-2/round-7 verified kernel)
#define RD_A(cb, qm)                                                     \
  {                                                                      \
    _Pragma("unroll") for (int f_ = 0; f_ < 4; f_++) {                   \
      _Pragma("unroll") for (int ks_ = 0; ks_ < 2; ks_++) {              \
        Ar[f_][ks_] = *(const short8*)(ldsb + (cb) * 65536 +             \
            (wm * 128 + (qm) * 64 + f_ * 16 + r15) * 128 +               \
            (((ks_ * 4 + l4) ^ lx) << 4));                               \
      }                                                                  \
    }                                                                    \
  }

#define RD_B(cb, qn, Brg)                                                \
  {                                                                      \
    _Pragma("unroll") for (int g_ = 0; g_ < 2; g_++) {                   \
      _Pragma("unroll") for (int ks_ = 0; ks_ < 2; ks_++) {              \
        Brg[g_][ks_] = *(const short8*)(ldsb + (cb) * 65536 + 32768 +    \
            (wn * 64 + (qn) * 32 + g_ * 16 + r15) * 128 +                \
            (((ks_ * 4 + l4) ^ lx) << 4));                               \
      }                                                                  \
    }                                                                    \
  }

#define MM(qm, qn, B)                                                    \
  {                                                                      \
    _Pragma("unroll") for (int f_ = 0; f_ < 4; f_++) {                   \
      _Pragma("unroll") for (int g_ = 0; g_ < 2; g_++) {                 \
        acc[(qm) * 4 + f_][(qn) * 2 + g_] =                              \
            __builtin_amdgcn_mfma_f32_16x16x32_bf16(                     \
                Ar[f_][0], B[g_][0], acc[(qm) * 4 + f_][(qn) * 2 + g_],  \
                0, 0, 0);                                                \
        acc[(qm) * 4 + f_][(qn) * 2 + g_] =                              \
            __builtin_amdgcn_mfma_f32_16x16x32_bf16(                     \
                Ar[f_][1], B[g_][1], acc[(qm) * 4 + f_][(qn) * 2 + g_],  \
                0, 0, 0);                                                \
      }                                                                  \
    }                                                                    \
  }

template <bool OUT_BF16>
__global__ __launch_bounds__(512, 2) void gemm256_8ph(
    const __hip_bfloat16* __restrict__ A, const __hip_bfloat16* __restrict__ Bt,
    void* __restrict__ C, int Nsplit, int ldc,
    void* __restrict__ C2, int ldc2, int N2,
    int K, int lda, int nbx) {
  __shared__ __hip_bfloat16 lds[2][2][16384];  // [buf][A|B][256*64]
  const int tid = threadIdx.x;
  const int lane = tid & 63;
  const int wave = tid >> 6;
  const int wm = wave >> 2;  // 0..1
  const int wn = wave & 3;   // 0..3
  const int r15 = lane & 15;
  const int l4 = lane >> 4;
  const int lx = lane & 7;

  // XCD-chunked block swizzle (bijective when gridDim %8 == 0).
  const int nwg = gridDim.x;
  int wg = blockIdx.x;
  if ((nwg & 7) == 0) wg = (wg & 7) * (nwg >> 3) + (wg >> 3);
  const int by = wg / nbx;
  const int bx = wg - by * nbx;
  const int m0 = by * 256;
  const int n0 = bx * 256;

  const int lr0 = tid >> 3;
  const int sg0 = (tid & 7) ^ (lr0 & 7);
  const __hip_bfloat16* aSrc = A + (size_t)(m0 + lr0) * lda + sg0 * 8;
  const __hip_bfloat16* bSrc = Bt + (size_t)(n0 + lr0) * (size_t)K + sg0 * 8;

  auto stageA = [&](int cb, int h, int kt) {
#pragma unroll
    for (int i = 0; i < 2; i++) {
      const __hip_bfloat16* src = aSrc + (size_t)((h * 128 + i * 64) * lda + kt);
      __builtin_amdgcn_global_load_lds(
          (const __attribute__((address_space(1))) void*)src,
          (__attribute__((address_space(3))) void*)&lds[cb][0]
              [h * 8192 + (i * 512 + tid) * 8],
          16, 0, 0);
    }
  };
  auto stageB = [&](int cb, int h, int kt) {
#pragma unroll
    for (int i = 0; i < 2; i++) {
      const __hip_bfloat16* src = bSrc + (size_t)((h * 128 + i * 64) * K + kt);
      __builtin_amdgcn_global_load_lds(
          (const __attribute__((address_space(1))) void*)src,
          (__attribute__((address_space(3))) void*)&lds[cb][1]
              [h * 8192 + (i * 512 + tid) * 8],
          16, 0, 0);
    }
  };

  floatx4 acc[8][4] = {};
  short8 Ar[4][2], Br0[2][2], Br1[2][2];
  const char* ldsb = (const char*)&lds[0][0][0];

  // Prologue: buf0 = tile0 (B then A), buf1.B = tile1. 12 loads/thread.
  stageB(0, 0, 0); stageB(0, 1, 0);
  stageA(0, 0, 0); stageA(0, 1, 0);
  stageB(1, 0, 64); stageB(1, 1, 64);
  VMC(4);
  BAR();

  const int niter = K >> 7;
#pragma unroll 1
  for (int it = 0; it < niter; ++it) {
    const int ktc = it * 128;
    const int kt1 = ktc + 64;
    const int t0n = (ktc + 128 < K) ? ktc + 128 : 0;
    const int t1n = (ktc + 192 < K) ? ktc + 192 : 0;

    RD_A(0, 0); RD_B(0, 0, Br0);
    stageA(1, 0, kt1);
    BAR(); LGKM0();
    __builtin_amdgcn_s_setprio(1); MM(0, 0, Br0); __builtin_amdgcn_s_setprio(0);
    BAR();
    RD_B(0, 1, Br1);
    stageA(1, 1, kt1);
    BAR(); LGKM0();
    __builtin_amdgcn_s_setprio(1); MM(0, 1, Br1); __builtin_amdgcn_s_setprio(0);
    BAR();
    RD_A(0, 1);
    stageB(0, 0, t0n);
    BAR(); LGKM0();
    __builtin_amdgcn_s_setprio(1); MM(1, 1, Br1); __builtin_amdgcn_s_setprio(0);
    BAR();
    stageB(0, 1, t0n);
    BAR();
    __builtin_amdgcn_s_setprio(1); MM(1, 0, Br0); __builtin_amdgcn_s_setprio(0);
    VMC(4);
    BAR();
    RD_A(1, 0); RD_B(1, 0, Br0);
    stageA(0, 0, t0n);
    BAR(); LGKM0();
    __builtin_amdgcn_s_setprio(1); MM(0, 0, Br0); __builtin_amdgcn_s_setprio(0);
    BAR();
    RD_B(1, 1, Br1);
    stageA(0, 1, t0n);
    BAR(); LGKM0();
    __builtin_amdgcn_s_setprio(1); MM(0, 1, Br1); __builtin_amdgcn_s_setprio(0);
    BAR();
    RD_A(1, 1);
    stageB(1, 0, t1n);
    BAR(); LGKM0();
    __builtin_amdgcn_s_setprio(1); MM(1, 1, Br1); __builtin_amdgcn_s_setprio(0);
    BAR();
    stageB(1, 1, t1n);
    BAR();
    __builtin_amdgcn_s_setprio(1); MM(1, 0, Br0); __builtin_amdgcn_s_setprio(0);
    VMC(4);
    BAR();
  }
  VMC(0);

  const int crow = l4 * 4;
#pragma unroll
  for (int f = 0; f < 8; f++) {
#pragma unroll
    for (int g = 0; g < 4; g++) {
      const int col = n0 + wn * 64 + g * 16 + r15;
      if (col < Nsplit) {
#pragma unroll
        for (int r = 0; r < 4; r++) {
          const size_t row = (size_t)(m0 + wm * 128 + f * 16 + crow + r);
          if (OUT_BF16)
            ((__hip_bfloat16*)C)[row * ldc + col] =
                __float2bfloat16(acc[f][g][r]);
          else
            ((float*)C)[row * ldc + col] = acc[f][g][r];
        }
      } else if (col - Nsplit < N2) {
        const int c2 = col - Nsplit;
#pragma unroll
        for (int r = 0; r < 4; r++) {
          const size_t row = (size_t)(m0 + wm * 128 + f * 16 + crow + r);
          if (OUT_BF16)
            ((__hip_bfloat16*)C2)[row * ldc2 + c2] =
                __float2bfloat16(acc[f][g][r]);
          else
            ((float*)C2)[row * ldc2 + c2] = acc[f][g][r];
        }
      }
    }
  }
}

// -------------------- weight transpose + cast ------------------------------
__global__ __launch_bounds__(256) void transpose_cast(
    const float* __restrict__ in, __hip_bfloat16* __restrict__ out, int K,
    int N) {
  __shared__ float tile[32][33];
  const int n0 = blockIdx.x * 32, k0 = blockIdx.y * 32;
  const int tx = threadIdx.x & 31, ty = threadIdx.x >> 5;
#pragma unroll
  for (int r = 0; r < 32; r += 8) {
    const int k = k0 + ty + r, n = n0 + tx;
    tile[ty + r][tx] = (n < N) ? in[(size_t)k * N + n] : 0.f;
  }
  __syncthreads();
#pragma unroll
  for (int r = 0; r < 32; r += 8) {
    const int n = n0 + ty + r, k = k0 + tx;
    out[(size_t)n * K + k] = __float2bfloat16(tile[tx][ty + r]);
  }
}

// -------------------- x cast (8 elems/thread, packed short8 store) ---------
__global__ __launch_bounds__(256) void cast_f32_bf16(
    const float* __restrict__ in, __hip_bfloat16* __restrict__ out) {
  const size_t i = ((size_t)blockIdx.x * 256 + threadIdx.x) * 8;
  const float4 v0 = *(const float4*)(in + i);
  const float4 v1 = *(const float4*)(in + i + 4);
  const float f[8] = {v0.x, v0.y, v0.z, v0.w, v1.x, v1.y, v1.z, v1.w};
  short8 o;
#pragma unroll
  for (int k = 0; k < 8; k++) {
    const __hip_bfloat16 b = __float2bfloat16(f[k]);
    o[k] = *(const short*)&b;
  }
  *(short8*)(out + i) = o;
}

// -------------------- RMSNorm (bf16 in-place, short8 vectorized) -----------
__global__ __launch_bounds__(256) void rmsnorm_bf16(
    __hip_bfloat16* __restrict__ x, const float* __restrict__ w, int ncols,
    int stride) {
  __hip_bfloat16* xr = x + (size_t)blockIdx.x * stride;
  float ss = 0.f;
  for (int c = threadIdx.x * 8; c < ncols; c += 2048) {
    const short8 v = *(const short8*)(xr + c);
#pragma unroll
    for (int k = 0; k < 8; k++) {
      const float f = bfbits2f((unsigned short)v[k]);
      ss += f * f;
    }
  }
#pragma unroll
  for (int off = 32; off > 0; off >>= 1) ss += __shfl_down(ss, off);
  __shared__ float wsum[4];
  __shared__ float scale_sh;
  const int wv = threadIdx.x >> 6, lane = threadIdx.x & 63;
  if (lane == 0) wsum[wv] = ss;
  __syncthreads();
  if (threadIdx.x == 0) {
    const float tot = wsum[0] + wsum[1] + wsum[2] + wsum[3];
    scale_sh = rsqrtf(tot / (float)ncols + 1e-6f);
  }
  __syncthreads();
  const float scale = scale_sh;
  for (int c = threadIdx.x * 8; c < ncols; c += 2048) {
    const short8 v = *(const short8*)(xr + c);
    short8 o;
#pragma unroll
    for (int k = 0; k < 8; k++) {
      float f = bfbits2f((unsigned short)v[k]) * scale;
      if (w) f *= w[c + k];
      const __hip_bfloat16 b = __float2bfloat16(f);
      o[k] = *(const short*)&b;
    }
    *(short8*)(xr + c) = o;
  }
}

// -------------------- RoPE cos/sin table (double math, once per (pos,i)) ---
__global__ __launch_bounds__(256) void build_rope_tab(
    float2* __restrict__ tab, const int* __restrict__ start_pos_p) {
  const int idx = blockIdx.x * 256 + threadIdx.x;  // 4096*32
  const int i = idx & 31;
  const int p = idx >> 5;
  const int pos = p + start_pos_p[0];
  const double theta = pow(10000.0, -(double)i / 32.0);
  const double ang = (double)pos * theta;
  tab[idx] = make_float2((float)cos(ang), (float)sin(ang));
}

// -------------------- RoPE on q (bug-compatible positions, table) ----------
__global__ __launch_bounds__(256) void rope_q_bf16(
    __hip_bfloat16* __restrict__ q, const float2* __restrict__ tab, int t0) {
  const int idx = blockIdx.x * 256 + threadIdx.x;  // Tc*16*32
  const int i = idx & 31;
  const int th = idx >> 5;
  const int t = th >> 4;
  const int h = th & 15;
  const int s_idx = (t0 + t) & 4095;
  const int p = (s_idx * 16 + h) & 4095;
  const float2 cs = tab[p * 32 + i];
  const float c = cs.x, s = cs.y;
  __hip_bfloat16* base = q + (size_t)t * 3072 + h * 192 + 128;
  const float x1 = __bfloat162float(base[i]);
  const float x2 = __bfloat162float(base[i + 32]);
  base[i] = __float2bfloat16(x1 * c - x2 * s);
  base[i + 32] = __float2bfloat16(x2 * c + x1 * s);
}

// -------------------- fused RoPE(k_pe) + RMSNorm(kv_c) ---------------------
__global__ __launch_bounds__(128) void rope_rms_kv(
    __hip_bfloat16* __restrict__ kv, const float2* __restrict__ tab) {
  __hip_bfloat16* xr = kv + (size_t)blockIdx.x * 576;
  const int tid = threadIdx.x;
  __shared__ float scale_sh;
  float ss = 0.f;
  short8 v;
  if (tid < 64) {
    v = *(const short8*)(xr + tid * 8);
#pragma unroll
    for (int k = 0; k < 8; k++) {
      const float f = bfbits2f((unsigned short)v[k]);
      ss += f * f;
    }
  } else if (tid < 96) {
    const int i = tid - 64;
    const float2 cs = tab[i];
    __hip_bfloat16* base = xr + 512;
    const float x1 = __bfloat162float(base[i]);
    const float x2 = __bfloat162float(base[i + 32]);
    base[i] = __float2bfloat16(x1 * cs.x - x2 * cs.y);
    base[i + 32] = __float2bfloat16(x2 * cs.x + x1 * cs.y);
  }
#pragma unroll
  for (int off = 32; off > 0; off >>= 1) ss += __shfl_down(ss, off);
  if (tid == 0) scale_sh = rsqrtf(ss / 512.f + 1e-6f);
  __syncthreads();
  if (tid < 64) {
    const float scale = scale_sh;
    short8 o;
#pragma unroll
    for (int k = 0; k < 8; k++) {
      const __hip_bfloat16 b =
          __float2bfloat16(bfbits2f((unsigned short)v[k]) * scale);
      o[k] = *(const short*)&b;
    }
    *(short8*)(xr + tid * 8) = o;
  }
}

// -------------------- wave-per-token attention (MFMA QK^T) -----------------
// S[qh][kh] = Q[qh] . K[kh] over 192 dims via 6x mfma_f32_16x16x32_bf16.
// Fragment mapping (verified by the GEMM on this harness): A/B operand:
// row(col)=lane&15, k=(lane>>4)*8+j per K=32 slice; C/D: col=lane&15,
// row=(lane>>4)*4+reg. Softmax reduces over kh = shfl_xor(1,2,4,8).
// PV stays VALU (f32 P from LDS, V from su) — numerics same as r7.
__global__ __launch_bounds__(256) void attn_wave_token(
    const __hip_bfloat16* __restrict__ q,     // [T][16][192]
    const __hip_bfloat16* __restrict__ kvup,  // [T][16][256] (k_nope|v)
    const __hip_bfloat16* __restrict__ kv,    // [T][576], k_pe at +512
    __hip_bfloat16* __restrict__ ctx) {       // [T][16][128]
  __shared__ __hip_bfloat16 sq[4][16 * 200];
  __shared__ __hip_bfloat16 su[4][16 * 264];
  __shared__ __hip_bfloat16 skpe[4][64];
  __shared__ float sp[4][16][20];  // padded: rows 80B (16B-aligned float4)
  const int tid = threadIdx.x;
  const int w = tid >> 6;
  const int lane = tid & 63;
  const int t = blockIdx.x * 4 + w;

  const __hip_bfloat16* qb = q + (size_t)t * 3072;
  const __hip_bfloat16* ub = kvup + (size_t)t * 4096;
#pragma unroll
  for (int i = 0; i < 6; i++) {
    const int u = lane + 64 * i;  // u < 384
    const int row = u / 24;
    *(short8*)(&sq[w][u * 8 + row * 8]) = *(const short8*)(qb + u * 8);
  }
#pragma unroll
  for (int i = 0; i < 8; i++) {
    const int u = lane + 64 * i;  // u < 512
    const int row = u >> 5;
    *(short8*)(&su[w][u * 8 + row * 8]) = *(const short8*)(ub + u * 8);
  }
  if (lane < 8)
    *(short8*)(&skpe[w][lane * 8]) =
        *(const short8*)(kv + (size_t)t * 576 + 512 + lane * 8);
  __syncthreads();

  const int r15 = lane & 15;
  const int l4 = lane >> 4;

  // ---- QK^T via MFMA: 4 slices from k_nope + 2 from k_pe (broadcast) ----
  floatx4 sacc = {0.f, 0.f, 0.f, 0.f};
#pragma unroll
  for (int ks = 0; ks < 4; ks++) {
    const short8 aq = *(const short8*)(&sq[w][r15 * 200 + ks * 32 + l4 * 8]);
    const short8 bk = *(const short8*)(&su[w][r15 * 264 + ks * 32 + l4 * 8]);
    sacc = __builtin_amdgcn_mfma_f32_16x16x32_bf16(aq, bk, sacc, 0, 0, 0);
  }
#pragma unroll
  for (int ks = 4; ks < 6; ks++) {
    const short8 aq = *(const short8*)(&sq[w][r15 * 200 + ks * 32 + l4 * 8]);
    const short8 bk = *(const short8*)(&skpe[w][(ks - 4) * 32 + l4 * 8]);
    sacc = __builtin_amdgcn_mfma_f32_16x16x32_bf16(aq, bk, sacc, 0, 0, 0);
  }

  // ---- softmax over kh: lane holds S[4*l4+reg][r15]; reduce over r15 ----
  const float scale = 0.07216878364870323f;  // 1/sqrt(192)
  float sv4[4];
#pragma unroll
  for (int r = 0; r < 4; r++) sv4[r] = sacc[r] * scale;
  float mx[4];
#pragma unroll
  for (int r = 0; r < 4; r++) {
    float m = sv4[r];
    m = fmaxf(m, __shfl_xor(m, 1));
    m = fmaxf(m, __shfl_xor(m, 2));
    m = fmaxf(m, __shfl_xor(m, 4));
    m = fmaxf(m, __shfl_xor(m, 8));
    mx[r] = m;
  }
  float e[4];
#pragma unroll
  for (int r = 0; r < 4; r++) {
    e[r] = expf(sv4[r] - mx[r]);
    float s = e[r];
    s += __shfl_xor(s, 1);
    s += __shfl_xor(s, 2);
    s += __shfl_xor(s, 4);
    s += __shfl_xor(s, 8);
    e[r] *= (1.0f / s);
  }
#pragma unroll
  for (int r = 0; r < 4; r++) sp[w][l4 * 4 + r][r15] = e[r];
  __syncthreads();

  // ---- PV (VALU): ctx[hh][d0..d0+3] = sum_j P[hh][j] * V[j][d0..d0+3] ----
  const int d0 = (lane & 31) * 4;
  float vreg[16][4];
#pragma unroll
  for (int j = 0; j < 16; j++) {
    const short4x v4 = *(const short4x*)(&su[w][j * 264 + 128 + d0]);
#pragma unroll
    for (int k = 0; k < 4; k++) vreg[j][k] = bfbits2f((unsigned short)v4[k]);
  }
  const int hb = (lane >> 5) * 8;
  __hip_bfloat16* cb = ctx + (size_t)t * 2048;
#pragma unroll
  for (int g = 0; g < 8; g++) {
    const int hh = hb + g;
    float o[4] = {0.f, 0.f, 0.f, 0.f};
#pragma unroll
    for (int j4 = 0; j4 < 4; j4++) {
      const float4 p4 = *(const float4*)(&sp[w][hh][j4 * 4]);
      const float pj[4] = {p4.x, p4.y, p4.z, p4.w};
#pragma unroll
      for (int jj = 0; jj < 4; jj++) {
        const int j = j4 * 4 + jj;
#pragma unroll
        for (int k = 0; k < 4; k++) o[k] += pj[jj] * vreg[j][k];
      }
    }
    short4x st;
#pragma unroll
    for (int k = 0; k < 4; k++) {
      const __hip_bfloat16 b = __float2bfloat16(o[k]);
      st[k] = *(const short*)&b;
    }
    *(short4x*)(cb + hh * 128 + d0) = st;
  }
}

// ---------------------------------------------------------------------------
extern "C" void kernel_launch(void* const* d_in, const int* in_sizes, int n_in,
                              void* d_out, int out_size, void* d_ws,
                              size_t ws_size, hipStream_t stream) {
  const float* x = (const float*)d_in[0];          // 16384 x 2048
  const float* wq_a = (const float*)d_in[1];       // 2048 x 1536
  const float* q_norm_w = (const float*)d_in[2];   // 1536
  const float* wq_b = (const float*)d_in[3];       // 1536 x 3072
  const float* wkv_a = (const float*)d_in[4];      // 2048 x 576
  const float* wkv_b = (const float*)d_in[5];      // 512 x 4096
  const float* wo = (const float*)d_in[6];         // 2048 x 2048
  const int* start_pos = (const int*)d_in[7];
  float* out = (float*)d_out;

  const int T = 16384;
  __hip_bfloat16* w0 = (__hip_bfloat16*)d_ws;
  __hip_bfloat16* wqkv_aT = w0;                      // 2304 x 2048
  __hip_bfloat16* wq_aT = wqkv_aT;                   // rows 0..1535
  __hip_bfloat16* wkv_aT = wqkv_aT + 1536 * 2048;    // rows 1536..2303 (pad)
  __hip_bfloat16* wq_bT = wqkv_aT + 2304 * 2048;     // 3072 x 1536
  __hip_bfloat16* wkv_bT = wq_bT + 3072 * 1536;      // 4096 x 512
  __hip_bfloat16* woT = wkv_bT + 4096 * 512;         // 2048 x 2048
  float2* rope_tab = (float2*)(woT + 2048 * 2048);   // 4096 x 32 float2 (1MB)
  __hip_bfloat16* chunk0 = (__hip_bfloat16*)(rope_tab + 4096 * 32);
  const size_t w_bytes = (size_t)((char*)chunk0 - (char*)w0);

  const size_t per_tok = 11840 * sizeof(__hip_bfloat16);
  int Tc = T;
  while (Tc > 256 && w_bytes + (size_t)Tc * per_tok > ws_size) Tc >>= 1;

  __hip_bfloat16* xb = chunk0;                       // Tc x 2048
  __hip_bfloat16* q_buf = xb + (size_t)Tc * 2048;    // Tc x 3072
  __hip_bfloat16* kvup = q_buf + (size_t)Tc * 3072;  // Tc x 4096
  __hip_bfloat16* cbuf = kvup + (size_t)Tc * 4096;   // Tc x 2048
  __hip_bfloat16* kv = cbuf + (size_t)Tc * 2048;     // Tc x 576

  dim3 blk(256);
  dim3 blk512(512);

  transpose_cast<<<dim3(1536 / 32, 2048 / 32), blk, 0, stream>>>(wq_a, wq_aT,
                                                                 2048, 1536);
  transpose_cast<<<dim3(768 / 32, 2048 / 32), blk, 0, stream>>>(wkv_a, wkv_aT,
                                                                2048, 576);
  transpose_cast<<<dim3(3072 / 32, 1536 / 32), blk, 0, stream>>>(wq_b, wq_bT,
                                                                 1536, 3072);
  transpose_cast<<<dim3(4096 / 32, 512 / 32), blk, 0, stream>>>(wkv_b, wkv_bT,
                                                                512, 4096);
  transpose_cast<<<dim3(2048 / 32, 2048 / 32), blk, 0, stream>>>(wo, woT, 2048,
                                                                 2048);
  build_rope_tab<<<(4096 * 32) / 256, blk, 0, stream>>>(rope_tab, start_pos);

  const int nby = Tc / 256;
  for (int t0 = 0; t0 < T; t0 += Tc) {
    cast_f32_bf16<<<(Tc * 2048) / 2048, blk, 0, stream>>>(
        x + (size_t)t0 * 2048, xb);
    // G1+G3 fused: [q_lora | kv] = xb @ [wq_a | wkv_a]^T
    gemm256_8ph<true><<<dim3(9 * nby), blk512, 0, stream>>>(
        xb, wqkv_aT, cbuf, 1536, 1536, kv, 576, 576, 2048, 2048, 9);
    rmsnorm_bf16<<<Tc, blk, 0, stream>>>(cbuf, q_norm_w, 1536, 1536);
    rope_rms_kv<<<Tc, dim3(128), 0, stream>>>(kv, rope_tab);
    // G2: q = q_lora @ wq_b^T
    gemm256_8ph<true><<<dim3(12 * nby), blk512, 0, stream>>>(
        cbuf, wq_bT, q_buf, 3072, 3072, nullptr, 0, 0, 1536, 1536, 12);
    rope_q_bf16<<<(Tc * 16 * 32) / 256, blk, 0, stream>>>(q_buf, rope_tab, t0);
    // G4: kvup = kvn @ wkv_b^T (A ld 576, K=512)
    gemm256_8ph<true><<<dim3(16 * nby), blk512, 0, stream>>>(
        kv, wkv_bT, kvup, 4096, 4096, nullptr, 0, 0, 512, 576, 16);
    // attention -> ctx (reuses cbuf)
    attn_wave_token<<<Tc / 4, blk, 0, stream>>>(q_buf, kvup, kv, cbuf);
    // G5: out = ctx @ wo^T (fp32 out)
    gemm256_8ph<false><<<dim3(8 * nby), blk512, 0, stream>>>(
        cbuf, woT, out + (size_t)t0 * 2048, 2048, 2048, nullptr, 0, 0, 2048,
        2048, 8);
  }
}